// Round 2
// baseline (7992.219 us; speedup 1.0000x reference)
//
#include <hip/hip_runtime.h>
#include <math.h>

#define BB 32
#define NNODE 512
#define TIN 12
#define CCH 32
#define NH 4
#define DDIM 32
#define NL 8
#define SKC 256
#define ENDC 512
#define ODIM 12
#define RFP 13

__device__ __forceinline__ float sigmoidf_(float x){ return 1.0f/(1.0f+expf(-x)); }

// ---------------- zero fill ----------------
__global__ void k_zero(float* __restrict__ p, int n){
  int i = blockIdx.x*256 + threadIdx.x;
  if (i < n) p[i] = 0.f;
}

// ---------------- feature -> l, r ----------------
__global__ void k_feat_lr(const float* __restrict__ input, const float* __restrict__ emb,
                          const float* __restrict__ embds_w, const float* __restrict__ embds_b,
                          const float* __restrict__ wl_w, const float* __restrict__ wl_b,
                          const float* __restrict__ wr_w, const float* __restrict__ wr_b,
                          float* __restrict__ lbuf, float* __restrict__ rbuf){
  int bn = blockIdx.x;          // b*N + n
  int b = bn >> 9, n = bn & 511;
  int j = threadIdx.x;          // 0..127
  __shared__ float f[TIN];
  if (j < TIN){
    float s = 0.f;
    for (int t = 0; t < TIN; ++t) s += input[(b*TIN + t)*NNODE + n] * embds_w[t];
    f[j] = s + embds_b[0] + emb[n*TIN + j];
  }
  __syncthreads();
  float lv = wl_b[j], rv = wr_b[j];
  for (int t = 0; t < TIN; ++t){
    float ft = f[t];
    lv += ft * wl_w[t*128 + j];
    rv += ft * wr_w[t*128 + j];
  }
  int h = j >> 5, d = j & 31;
  int o = ((b*NH + h)*NNODE + n)*DDIM + d;
  lbuf[o] = lv; rbuf[o] = rv;
}

// ---------------- att = l r^T / sqrt(32) ----------------
__global__ __launch_bounds__(256) void k_att(const float* __restrict__ lbuf,
                      const float* __restrict__ rbuf, float* __restrict__ att){
  int bh = blockIdx.z;
  int n0 = blockIdx.y * 16, m0 = blockIdx.x * 16;
  int tx = threadIdx.x, ty = threadIdx.y;   // 16x16
  __shared__ float Ls[16][33], Rs[16][33];
  const float* lb = lbuf + (size_t)bh*NNODE*DDIM;
  const float* rb = rbuf + (size_t)bh*NNODE*DDIM;
  Ls[ty][tx]    = lb[(n0+ty)*DDIM + tx];
  Ls[ty][tx+16] = lb[(n0+ty)*DDIM + tx+16];
  Rs[ty][tx]    = rb[(m0+ty)*DDIM + tx];
  Rs[ty][tx+16] = rb[(m0+ty)*DDIM + tx+16];
  __syncthreads();
  float s = 0.f;
  #pragma unroll
  for (int d = 0; d < 32; ++d) s += Ls[ty][d] * Rs[tx][d];
  att[((size_t)bh*NNODE + n0+ty)*NNODE + m0 + tx] = s / sqrtf(32.0f);
}

// ---------------- per-row exact top-k + softmax (in place) ----------------
__global__ __launch_bounds__(256) void k_topk_softmax(float* __restrict__ att){
  int row = blockIdx.x;                 // (b*H + h)*N + n
  int h = (row >> 9) & 3;
  int k = (h==0)?10:(h==1)?20:(h==2)?40:500;
  float* rp = att + (size_t)row * NNODE;
  __shared__ float vals[NNODE];
  __shared__ float srt[NNODE];
  __shared__ float red[256];
  __shared__ int gcnt;
  int tid = threadIdx.x;
  for (int i = tid; i < NNODE; i += 256){ float v = rp[i]; vals[i] = v; srt[i] = v; }
  if (tid == 0) gcnt = 0;
  __syncthreads();
  // bitonic sort descending
  for (int size = 2; size <= NNODE; size <<= 1){
    for (int stride = size >> 1; stride > 0; stride >>= 1){
      for (int i = tid; i < NNODE; i += 256){
        int j = i ^ stride;
        if (j > i){
          bool dirDesc = ((i & size) == 0);
          float a = srt[i], bv = srt[j];
          bool sw = dirDesc ? (a < bv) : (a > bv);
          if (sw){ srt[i] = bv; srt[j] = a; }
        }
      }
      __syncthreads();
    }
  }
  float thresh = srt[k-1];
  float mx = srt[0];
  int lc = 0;
  for (int i = tid; i < NNODE; i += 256) if (srt[i] > thresh) lc++;
  atomicAdd(&gcnt, lc);
  __syncthreads();
  int neq = k - gcnt;   // # ties to keep, lowest index first (top_k stable order)
  float e0[2];
  float lsum = 0.f;
  for (int ii = 0; ii < 2; ++ii){
    int i = tid + ii*256;
    float v = vals[i];
    bool keep = v > thresh;
    if (!keep && v == thresh){
      int rank = 0;
      for (int jj = 0; jj < i; ++jj) if (vals[jj] == thresh) rank++;
      keep = rank < neq;
    }
    float e = keep ? expf(v - mx) : 0.f;
    e0[ii] = e; lsum += e;
  }
  red[tid] = lsum;
  __syncthreads();
  for (int s = 128; s > 0; s >>= 1){
    if (tid < s) red[tid] += red[tid + s];
    __syncthreads();
  }
  float tot = red[0];
  for (int ii = 0; ii < 2; ++ii){
    int i = tid + ii*256;
    rp[i] = e0[ii] / tot;
  }
}

// ---------------- sup: copy s0,s1 ----------------
__global__ void k_sup_copy(const float* __restrict__ supports, float* __restrict__ sup){
  int i = blockIdx.x*256 + threadIdx.x;
  const int nn = NNODE*NNODE;
  if (i < nn){
    sup[i] = supports[i];                 // s0 -> sup[0]
    sup[(size_t)2*nn + i] = supports[nn + i]; // s1 -> sup[2]
  }
}

// ---------------- sup squares: s@s ----------------
__global__ __launch_bounds__(256) void k_sup_sq(const float* __restrict__ supports,
                                                float* __restrict__ sup){
  int which = blockIdx.z;                 // 0 -> s0, 1 -> s1
  const float* A = supports + (size_t)which*NNODE*NNODE;
  float* Co = sup + (size_t)(2*which + 1)*NNODE*NNODE;
  int w0 = blockIdx.x * 32, v0 = blockIdx.y * 32;
  int tid = threadIdx.x;
  int tx = tid & 31, tyg = tid >> 5;      // 8 row-groups of 4 rows (stride 8)
  __shared__ float As[32][33], Bs[32][33];
  float acc[4] = {0.f,0.f,0.f,0.f};
  for (int k0 = 0; k0 < NNODE; k0 += 32){
    int lc = tid >> 3, lu0 = (tid & 7) * 4;
    for (int u = 0; u < 4; ++u){
      As[lc][lu0+u] = A[(size_t)(v0+lc)*NNODE + k0 + lu0 + u];
      Bs[lc][lu0+u] = A[(size_t)(k0+lc)*NNODE + w0 + lu0 + u];
    }
    __syncthreads();
    for (int u = 0; u < 32; ++u){
      float bw = Bs[u][tx];
      #pragma unroll
      for (int j = 0; j < 4; ++j) acc[j] += As[tyg + 8*j][u] * bw;
    }
    __syncthreads();
  }
  for (int j = 0; j < 4; ++j)
    Co[(size_t)(v0 + tyg + 8*j)*NNODE + w0 + tx] = acc[j];
}

// ---------------- x0 = start conv on left-padded input ----------------
__global__ void k_make_x0(const float* __restrict__ input, const float* __restrict__ start_w,
                          const float* __restrict__ start_b, float* __restrict__ x0){
  int idx = blockIdx.x*256 + threadIdx.x;
  const int total = BB*RFP*CCH*NNODE;
  if (idx >= total) return;
  int n = idx & 511;
  int rest = idx >> 9;
  int c = rest & 31; rest >>= 5;
  int t = rest % RFP;
  int b = rest / RFP;
  float v = (t == 0) ? 0.f : input[((size_t)b*TIN + (t-1))*NNODE + n];
  x0[idx] = start_w[c] * v + start_b[c];
}

// ---------------- dilated conv + tanh*sigmoid gate ----------------
__global__ __launch_bounds__(256) void k_dconv_act(const float* __restrict__ x,
      const float* __restrict__ fw, const float* __restrict__ fb,
      const float* __restrict__ gw, const float* __restrict__ gb,
      float* __restrict__ out, int Tin, int Tp, int dil){
  // grid: (N/64, Tp, B)
  int n0 = blockIdx.x * 64;
  int t = blockIdx.y;
  int b = blockIdx.z;
  int tid = threadIdx.x;
  int lane = tid & 63, cg = tid >> 6;
  __shared__ float X0[32][64], X1[32][64];
  __shared__ float fwl[32][32][2], gwl[32][32][2];
  const float* xb0 = x + ((size_t)(b*Tin + t)*CCH)*NNODE;
  const float* xb1 = x + ((size_t)(b*Tin + t + dil)*CCH)*NNODE;
  for (int i = tid; i < 32*64; i += 256){
    int c = i >> 6, nn2 = i & 63;
    X0[c][nn2] = xb0[c*NNODE + n0 + nn2];
    X1[c][nn2] = xb1[c*NNODE + n0 + nn2];
  }
  for (int i = tid; i < 2048; i += 256){
    ((float*)fwl)[i] = fw[i];
    ((float*)gwl)[i] = gw[i];
  }
  __syncthreads();
  float F[8], G[8];
  #pragma unroll
  for (int j = 0; j < 8; ++j){ int c = cg*8 + j; F[j] = fb[c]; G[j] = gb[c]; }
  for (int cp = 0; cp < 32; ++cp){
    float x0v = X0[cp][lane], x1v = X1[cp][lane];
    #pragma unroll
    for (int j = 0; j < 8; ++j){
      int c = cg*8 + j;
      F[j] += x0v * fwl[c][cp][0] + x1v * fwl[c][cp][1];
      G[j] += x0v * gwl[c][cp][0] + x1v * gwl[c][cp][1];
    }
  }
  float* ob = out + ((size_t)(b*Tp + t)*CCH)*NNODE;
  #pragma unroll
  for (int j = 0; j < 8; ++j){
    int c = cg*8 + j;
    ob[c*NNODE + n0 + lane] = tanhf(F[j]) * sigmoidf_(G[j]);
  }
}

// ---------------- skip accumulation at last time slice ----------------
__global__ __launch_bounds__(256) void k_skip_accum(const float* __restrict__ act,
     const float* __restrict__ sw, const float* __restrict__ sb,
     float* __restrict__ skip, int Tp){
  // grid: (N/64, 8, B)
  int n0 = blockIdx.x * 64;
  int e0 = blockIdx.y * 32;
  int b = blockIdx.z;
  int tid = threadIdx.x;
  int lane = tid & 63, eg = tid >> 6;
  __shared__ float Xs[32][64];
  const float* ab = act + ((size_t)(b*Tp + Tp-1)*CCH)*NNODE;
  for (int i = tid; i < 2048; i += 256){
    int c = i >> 6, nn2 = i & 63;
    Xs[c][nn2] = ab[c*NNODE + n0 + nn2];
  }
  __syncthreads();
  float acc[8];
  #pragma unroll
  for (int j = 0; j < 8; ++j) acc[j] = sb[e0 + eg*8 + j];
  for (int c = 0; c < 32; ++c){
    float xv = Xs[c][lane];
    #pragma unroll
    for (int j = 0; j < 8; ++j) acc[j] += sw[(e0 + eg*8 + j)*CCH + c] * xv;
  }
  #pragma unroll
  for (int j = 0; j < 8; ++j){
    int e = e0 + eg*8 + j;
    skip[((size_t)b*SKC + e)*NNODE + n0 + lane] += acc[j];
  }
}

// ---------------- fused GCN: out = bias + Wx·X + Σ_s (Ws·X)·A_s, opt res+bn ----------------
__global__ __launch_bounds__(256) void k_gcn(const float* __restrict__ X,
    const float* __restrict__ Abase, const float* __restrict__ w,
    const float* __restrict__ bias, float* __restrict__ out,
    const float* __restrict__ res, const float* __restrict__ bng,
    const float* __restrict__ bnb, int Tp, int dil, int batched){
  // grid: (2, B*Tp). Block computes out[32, 256] for one (b,t).
  int n0 = blockIdx.x * 256;
  int bt = blockIdx.y;
  int b = bt / Tp;
  const float* X_ = X + (size_t)bt*CCH*NNODE;
  int tid = threadIdx.x;
  int lane = tid & 63, og = tid >> 6;
  __shared__ float wl[32*161];                 // padded stride 161 (bank-conflict-free)
  __shared__ float As[32][256];
  __shared__ __align__(16) float Xs[32][36];
  __shared__ float Zs[32][33];
  for (int i = tid; i < 5120; i += 256){
    int o = i / 160, c = i - o*160;
    wl[o*161 + c] = w[i];
  }
  float acc[8][4];
  #pragma unroll
  for (int j = 0; j < 8; ++j){
    float bv = bias[og*8 + j];
    #pragma unroll
    for (int kq = 0; kq < 4; ++kq) acc[j][kq] = bv;
  }
  // pass 0: Wx · X : "A" tile = X columns n0.., Z = Wx (first 32 cols of w)
  for (int jj = 0; jj < 32; ++jj) As[jj][tid] = X_[jj*NNODE + n0 + tid];
  __syncthreads();
  for (int v = 0; v < 32; ++v){
    float zv[8];
    #pragma unroll
    for (int j = 0; j < 8; ++j) zv[j] = wl[(og*8 + j)*161 + v];
    #pragma unroll
    for (int kq = 0; kq < 4; ++kq){
      float a = As[v][lane + 64*kq];
      #pragma unroll
      for (int j = 0; j < 8; ++j) acc[j][kq] += zv[j] * a;
    }
  }
  // passes s = 0..3 over supports
  for (int s = 0; s < 4; ++s){
    const float* A = Abase + (batched ? (size_t)(b*NH + s) : (size_t)s)*NNODE*NNODE;
    for (int k0 = 0; k0 < NNODE; k0 += 32){
      __syncthreads();   // protect As/Xs/Zs from readers of previous iteration
      { int c = tid >> 3, v0 = (tid & 7) * 4;
        *reinterpret_cast<float4*>(&Xs[c][v0]) =
            *reinterpret_cast<const float4*>(X_ + c*NNODE + k0 + v0); }
      for (int jj = 0; jj < 32; ++jj)
        As[jj][tid] = A[(size_t)(k0 + jj)*NNODE + n0 + tid];
      __syncthreads();
      // Z tile: Zs[o][v] = Σ_c w[o, 32+32s+c] * Xs[c][v]
      { int o = tid >> 3, v0 = (tid & 7) * 4;
        const float* wrow = &wl[o*161 + 32 + 32*s];
        float z0=0.f, z1=0.f, z2=0.f, z3=0.f;
        #pragma unroll
        for (int c = 0; c < 32; ++c){
          float wv = wrow[c];
          z0 += wv*Xs[c][v0];   z1 += wv*Xs[c][v0+1];
          z2 += wv*Xs[c][v0+2]; z3 += wv*Xs[c][v0+3];
        }
        Zs[o][v0] = z0; Zs[o][v0+1] = z1; Zs[o][v0+2] = z2; Zs[o][v0+3] = z3;
      }
      __syncthreads();
      for (int v = 0; v < 32; ++v){
        float zv[8];
        #pragma unroll
        for (int j = 0; j < 8; ++j) zv[j] = Zs[og*8 + j][v];
        #pragma unroll
        for (int kq = 0; kq < 4; ++kq){
          float a = As[v][lane + 64*kq];
          #pragma unroll
          for (int j = 0; j < 8; ++j) acc[j][kq] += zv[j] * a;
        }
      }
    }
  }
  // epilogue
  float* ob = out + (size_t)bt*CCH*NNODE;
  if (res){
    int t = bt - b*Tp;
    const float* rb = res + ((size_t)(b*(Tp + dil) + t + dil)*CCH)*NNODE;
    const float inv = 1.0f / sqrtf(1.0f + 1e-5f);
    #pragma unroll
    for (int j = 0; j < 8; ++j){
      int o = og*8 + j;
      float g = bng[o]*inv, b2 = bnb[o];
      #pragma unroll
      for (int kq = 0; kq < 4; ++kq){
        float v = acc[j][kq] + rb[(size_t)o*NNODE + n0 + lane + 64*kq];
        ob[(size_t)o*NNODE + n0 + lane + 64*kq] = v * g + b2;
      }
    }
  } else {
    #pragma unroll
    for (int j = 0; j < 8; ++j){
      int o = og*8 + j;
      #pragma unroll
      for (int kq = 0; kq < 4; ++kq)
        ob[(size_t)o*NNODE + n0 + lane + 64*kq] = acc[j][kq];
    }
  }
}

// ---------------- end MLP: relu(skip) -> relu(end1) -> end2 ----------------
__global__ __launch_bounds__(256) void k_end(const float* __restrict__ skip,
    const float* __restrict__ e1w, const float* __restrict__ e1b,
    const float* __restrict__ e2w, const float* __restrict__ e2b,
    float* __restrict__ out){
  // grid: (N/16, B)
  int n0 = blockIdx.x * 16;
  int b = blockIdx.y;
  int tid = threadIdx.x;
  __shared__ float sk[SKC][17];
  __shared__ float hid[ENDC][17];
  for (int i = tid; i < SKC*16; i += 256){
    int s = i >> 4, nn2 = i & 15;
    float v = skip[((size_t)b*SKC + s)*NNODE + n0 + nn2];
    sk[s][nn2] = v > 0.f ? v : 0.f;
  }
  __syncthreads();
  for (int i = tid; i < ENDC*16; i += 256){
    int e = i >> 4, nn2 = i & 15;
    float a = e1b[e];
    for (int s = 0; s < SKC; ++s) a += e1w[e*SKC + s] * sk[s][nn2];
    hid[e][nn2] = a > 0.f ? a : 0.f;
  }
  __syncthreads();
  if (tid < ODIM*16){
    int o = tid >> 4, nn2 = tid & 15;
    float a = e2b[o];
    for (int e = 0; e < ENDC; ++e) a += e2w[o*ENDC + e] * hid[e][nn2];
    out[((size_t)b*ODIM + o)*NNODE + n0 + nn2] = a;
  }
}

extern "C" void kernel_launch(void* const* d_in, const int* in_sizes, int n_in,
                              void* d_out, int out_size, void* d_ws, size_t ws_size,
                              hipStream_t stream){
  const float* input   = (const float*)d_in[0];
  const float* supports= (const float*)d_in[1];
  const float* emb     = (const float*)d_in[2];
  const float* embds_w = (const float*)d_in[3];
  const float* embds_b = (const float*)d_in[4];
  const float* wl_w    = (const float*)d_in[5];
  const float* wl_b    = (const float*)d_in[6];
  const float* wr_w    = (const float*)d_in[7];
  const float* wr_b    = (const float*)d_in[8];
  const float* start_w = (const float*)d_in[9];
  const float* start_b = (const float*)d_in[10];
  const float* filter_w= (const float*)d_in[11];
  const float* filter_b= (const float*)d_in[12];
  const float* gate_w  = (const float*)d_in[13];
  const float* gate_b  = (const float*)d_in[14];
  const float* skip_w  = (const float*)d_in[15];
  const float* skip_b  = (const float*)d_in[16];
  const float* bn_g    = (const float*)d_in[17];
  const float* bn_b    = (const float*)d_in[18];
  const float* gconv_w = (const float*)d_in[19];
  const float* gconv_b = (const float*)d_in[20];
  const float* dyn_w   = (const float*)d_in[21];
  const float* dyn_b   = (const float*)d_in[22];
  const float* end1_w  = (const float*)d_in[23];
  const float* end1_b  = (const float*)d_in[24];
  const float* end2_w  = (const float*)d_in[25];
  const float* end2_b  = (const float*)d_in[26];
  float* out = (float*)d_out;

  float* ws = (float*)d_ws;
  size_t off = 0;
  float* dyn  = ws + off; off += (size_t)BB*NH*NNODE*NNODE;   // 33,554,432
  float* sup  = ws + off; off += (size_t)4*NNODE*NNODE;       //  1,048,576
  float* bufP = ws + off; off += (size_t)BB*RFP*CCH*NNODE;    //  6,815,744
  float* bufQ = ws + off; off += (size_t)BB*RFP*CCH*NNODE;
  float* bufR = ws + off; off += (size_t)BB*RFP*CCH*NNODE;
  float* skip = ws + off; off += (size_t)BB*SKC*NNODE;        //  4,194,304
  // total 59,244,544 floats = 237.0 MB
  float* lbuf = bufQ;                       // dead after k_att; alias into bufQ
  float* rbuf = bufQ + (size_t)BB*NH*NNODE*DDIM;

  hipLaunchKernelGGL(k_feat_lr, dim3(BB*NNODE), dim3(128), 0, stream,
                     input, emb, embds_w, embds_b, wl_w, wl_b, wr_w, wr_b, lbuf, rbuf);
  hipLaunchKernelGGL(k_att, dim3(NNODE/16, NNODE/16, BB*NH), dim3(16,16), 0, stream,
                     lbuf, rbuf, dyn);
  hipLaunchKernelGGL(k_topk_softmax, dim3(BB*NH*NNODE), dim3(256), 0, stream, dyn);
  hipLaunchKernelGGL(k_sup_copy, dim3(1024), dim3(256), 0, stream, supports, sup);
  hipLaunchKernelGGL(k_sup_sq, dim3(16,16,2), dim3(256), 0, stream, supports, sup);
  {
    int total = BB*RFP*CCH*NNODE;
    hipLaunchKernelGGL(k_make_x0, dim3((total+255)/256), dim3(256), 0, stream,
                       input, start_w, start_b, bufP);
  }
  {
    int n = BB*SKC*NNODE;
    hipLaunchKernelGGL(k_zero, dim3((n+255)/256), dim3(256), 0, stream, skip, n);
  }

  const int dil[8] = {1,2,1,2,1,2,1,2};
  int T = RFP;
  float* P = bufP; float* Q = bufQ; float* R = bufR;
  for (int i = 0; i < NL; ++i){
    int d = dil[i], Tp = T - d;
    hipLaunchKernelGGL(k_dconv_act, dim3(NNODE/64, Tp, BB), dim3(256), 0, stream,
        P, filter_w + i*2048, filter_b + i*32, gate_w + i*2048, gate_b + i*32, Q, T, Tp, d);
    hipLaunchKernelGGL(k_skip_accum, dim3(NNODE/64, 8, BB), dim3(256), 0, stream,
        Q, skip_w + i*SKC*CCH, skip_b + i*SKC, skip, Tp);
    hipLaunchKernelGGL(k_gcn, dim3(2, BB*Tp), dim3(256), 0, stream,
        Q, dyn, dyn_w + i*CCH*5*CCH, dyn_b + i*CCH, R,
        (const float*)nullptr, (const float*)nullptr, (const float*)nullptr, Tp, d, 1);
    hipLaunchKernelGGL(k_gcn, dim3(2, BB*Tp), dim3(256), 0, stream,
        R, sup, gconv_w + i*CCH*5*CCH, gconv_b + i*CCH, Q,
        P, bn_g + i*CCH, bn_b + i*CCH, Tp, d, 0);
    float* tmp = P; P = Q; Q = tmp;
    T = Tp;
  }
  hipLaunchKernelGGL(k_end, dim3(NNODE/16, BB), dim3(256), 0, stream,
                     skip, end1_w, end1_b, end2_w, end2_b, out);
}

// Round 4
// 2826.629 us; speedup vs baseline: 2.8275x; 2.8275x over previous
//
#include <hip/hip_runtime.h>
#include <math.h>

#define BB 32
#define NNODE 512
#define TIN 12
#define CCH 32
#define NH 4
#define DDIM 32
#define NL 8
#define SKC 256
#define ENDC 512
#define ODIM 12
#define RFP 13

typedef __attribute__((ext_vector_type(8))) short bf16x8;
typedef __attribute__((ext_vector_type(4))) float f32x4;

__device__ __forceinline__ float sigmoidf_(float x){ return 1.0f/(1.0f+expf(-x)); }
__device__ __forceinline__ unsigned short f2bf(float f){
  unsigned u = __float_as_uint(f);
  u += 0x7FFFu + ((u >> 16) & 1u);
  return (unsigned short)(u >> 16);
}
__device__ __forceinline__ float bf2f(unsigned short h){
  return __uint_as_float(((unsigned)h) << 16);
}

// ---------------- zero fill ----------------
__global__ void k_zero(float* __restrict__ p, int n){
  int i = blockIdx.x*256 + threadIdx.x;
  if (i < n) p[i] = 0.f;
}

// ---------------- feature -> l, r ----------------
__global__ void k_feat_lr(const float* __restrict__ input, const float* __restrict__ emb,
                          const float* __restrict__ embds_w, const float* __restrict__ embds_b,
                          const float* __restrict__ wl_w, const float* __restrict__ wl_b,
                          const float* __restrict__ wr_w, const float* __restrict__ wr_b,
                          float* __restrict__ lbuf, float* __restrict__ rbuf){
  int bn = blockIdx.x;          // b*N + n
  int b = bn >> 9, n = bn & 511;
  int j = threadIdx.x;          // 0..127
  __shared__ float f[TIN];
  if (j < TIN){
    float s = 0.f;
    for (int t = 0; t < TIN; ++t) s += input[(b*TIN + t)*NNODE + n] * embds_w[t];
    f[j] = s + embds_b[0] + emb[n*TIN + j];
  }
  __syncthreads();
  float lv = wl_b[j], rv = wr_b[j];
  for (int t = 0; t < TIN; ++t){
    float ft = f[t];
    lv += ft * wl_w[t*128 + j];
    rv += ft * wr_w[t*128 + j];
  }
  int h = j >> 5, d = j & 31;
  int o = ((b*NH + h)*NNODE + n)*DDIM + d;
  lbuf[o] = lv; rbuf[o] = rv;
}

// ---------------- att = l r^T / sqrt(32), 32x32 tiles ----------------
__global__ __launch_bounds__(256) void k_att(const float* __restrict__ lbuf,
                      const float* __restrict__ rbuf, float* __restrict__ att){
  int bh = blockIdx.z;
  int n0 = blockIdx.y * 32, m0 = blockIdx.x * 32;
  int tid = threadIdx.x;
  int tx = tid & 31, ty = tid >> 5;   // 8 row-groups
  __shared__ float Ls[32][33], Rs[32][33];
  const float* lb = lbuf + (size_t)bh*NNODE*DDIM;
  const float* rb = rbuf + (size_t)bh*NNODE*DDIM;
  for (int i = tid; i < 1024; i += 256){
    int r = i >> 5, c = i & 31;
    Ls[r][c] = lb[(n0+r)*DDIM + c];
    Rs[r][c] = rb[(m0+r)*DDIM + c];
  }
  __syncthreads();
  float acc[4] = {0.f,0.f,0.f,0.f};
  for (int d = 0; d < 32; ++d){
    float rv = Rs[tx][d];
    #pragma unroll
    for (int j = 0; j < 4; ++j) acc[j] += Ls[ty + 8*j][d] * rv;
  }
  #pragma unroll
  for (int j = 0; j < 4; ++j)
    att[((size_t)bh*NNODE + n0+ty+8*j)*NNODE + m0 + tx] = acc[j] / sqrtf(32.0f);
}

// ---------------- per-row exact top-k (radix select) + softmax in place ----------------
__global__ __launch_bounds__(256) void k_topk_softmax(float* __restrict__ att){
  int row = blockIdx.x;                 // (b*H + h)*N + n
  int h = (row >> 9) & 3;
  int k = (h==0)?10:(h==1)?20:(h==2)?40:500;
  float* rp = att + (size_t)row * NNODE;
  __shared__ unsigned uv[NNODE];
  __shared__ int hist[256];
  __shared__ int sc[256];
  __shared__ unsigned s_pfx;
  __shared__ int s_kr, s_d;
  __shared__ float redm[4], reds[4];
  int tid = threadIdx.x;
  float v0 = rp[tid], v1 = rp[tid+256];
  unsigned a0 = __float_as_uint(v0); a0 = (a0 & 0x80000000u) ? ~a0 : (a0 | 0x80000000u);
  unsigned a1 = __float_as_uint(v1); a1 = (a1 & 0x80000000u) ? ~a1 : (a1 | 0x80000000u);
  uv[tid] = a0; uv[tid+256] = a1;
  float m = fmaxf(v0, v1);
  for (int off = 32; off; off >>= 1) m = fmaxf(m, __shfl_down(m, off, 64));
  if ((tid & 63) == 0) redm[tid >> 6] = m;
  if (tid == 0){ s_kr = k; s_pfx = 0u; }
  __syncthreads();
  float mx = fmaxf(fmaxf(redm[0], redm[1]), fmaxf(redm[2], redm[3]));
  for (int rnd = 0; rnd < 4; ++rnd){
    int sh = 24 - rnd*8;
    hist[tid] = 0;
    __syncthreads();
    unsigned pfx = s_pfx;
    bool c0 = (rnd == 0) || ((a0 >> (sh+8)) == (pfx >> (sh+8)));
    bool c1 = (rnd == 0) || ((a1 >> (sh+8)) == (pfx >> (sh+8)));
    if (c0) atomicAdd(&hist[(a0 >> sh) & 255], 1);
    if (c1) atomicAdd(&hist[(a1 >> sh) & 255], 1);
    __syncthreads();
    sc[tid] = hist[tid];
    __syncthreads();
    for (int off = 1; off < 256; off <<= 1){
      int y = (tid + off < 256) ? sc[tid + off] : 0;
      __syncthreads();
      sc[tid] += y;
      __syncthreads();
    }
    int kr = s_kr;
    int sAll = sc[tid];
    int sNext = (tid < 255) ? sc[tid+1] : 0;
    if (sAll >= kr && sNext < kr) s_d = tid;
    __syncthreads();
    int d = s_d;
    if (tid == 0){
      s_kr = kr - ((d < 255) ? sc[d+1] : 0);
      s_pfx = pfx | ((unsigned)d << sh);
    }
    __syncthreads();
  }
  unsigned uth = s_pfx;
  int neq = s_kr;     // ties kept, lowest index first
  float e0 = 0.f, e1 = 0.f;
  {
    bool keep = a0 > uth;
    if (!keep && a0 == uth){
      int rank = 0;
      for (int j = 0; j < tid; ++j) rank += (uv[j] == uth);
      keep = rank < neq;
    }
    if (keep) e0 = expf(v0 - mx);
  }
  {
    int i = tid + 256;
    bool keep = a1 > uth;
    if (!keep && a1 == uth){
      int rank = 0;
      for (int j = 0; j < i; ++j) rank += (uv[j] == uth);
      keep = rank < neq;
    }
    if (keep) e1 = expf(v1 - mx);
  }
  float s = e0 + e1;
  for (int off = 32; off; off >>= 1) s += __shfl_down(s, off, 64);
  if ((tid & 63) == 0) reds[tid >> 6] = s;
  __syncthreads();
  float tot = reds[0] + reds[1] + reds[2] + reds[3];
  rp[tid] = e0 / tot;
  rp[tid + 256] = e1 / tot;
}

// ---------------- transpose dyn (fp32 [bs][v][w]) -> dynT (bf16 [bs][w][v]) ----------------
__global__ __launch_bounds__(256) void k_transpose_dyn(const float* __restrict__ dyn,
                                                       unsigned short* __restrict__ dynT){
  int bs = blockIdx.z;
  int v0 = blockIdx.x*64, w0 = blockIdx.y*64;
  __shared__ float Ts[64][65];
  const float* S = dyn + (size_t)bs*NNODE*NNODE;
  unsigned short* D = dynT + (size_t)bs*NNODE*NNODE;
  int tid = threadIdx.x;
  for (int i = tid; i < 4096; i += 256){
    int r = i >> 6, c = i & 63;
    Ts[r][c] = S[(size_t)(v0+r)*NNODE + w0 + c];
  }
  __syncthreads();
  for (int i = tid; i < 4096; i += 256){
    int r = i >> 6, c = i & 63;
    D[(size_t)(w0+r)*NNODE + v0 + c] = f2bf(Ts[c][r]);
  }
}

// ---------------- supT: transpose s0, s1 into blocks 0, 2 ----------------
__global__ __launch_bounds__(256) void k_supT_copy(const float* __restrict__ supports,
                                                   unsigned short* __restrict__ supT){
  int w = blockIdx.z;                  // 0 -> s0 (block 0), 1 -> s1 (block 2)
  int v0 = blockIdx.x*64, n0 = blockIdx.y*64;
  __shared__ float Ts[64][65];
  const float* S = supports + (size_t)w*NNODE*NNODE;
  int tid = threadIdx.x;
  for (int i = tid; i < 4096; i += 256){
    int r = i >> 6, c = i & 63;
    Ts[r][c] = S[(size_t)(v0+r)*NNODE + n0 + c];
  }
  __syncthreads();
  for (int i = tid; i < 4096; i += 256){
    int r = i >> 6, c = i & 63;
    supT[((size_t)(2*w)*NNODE + n0 + r)*NNODE + v0 + c] = f2bf(Ts[c][r]);
  }
}

// ---------------- supT squares: s@s, transposed store into blocks 1, 3 ----------------
__global__ __launch_bounds__(256) void k_supT_sq(const float* __restrict__ supports,
                                                 unsigned short* __restrict__ supT){
  int which = blockIdx.z;              // 0 -> s0^2 (block 1), 1 -> s1^2 (block 3)
  const float* A = supports + (size_t)which*NNODE*NNODE;
  int w0 = blockIdx.x * 32, v0 = blockIdx.y * 32;
  int tid = threadIdx.x;
  int tx = tid & 31, tyg = tid >> 5;
  __shared__ float As[32][33], Bs[32][33], Cs[32][33];
  float acc[4] = {0.f,0.f,0.f,0.f};
  for (int k0 = 0; k0 < NNODE; k0 += 32){
    int lc = tid >> 3, lu0 = (tid & 7) * 4;
    __syncthreads();
    for (int u = 0; u < 4; ++u){
      As[lc][lu0+u] = A[(size_t)(v0+lc)*NNODE + k0 + lu0 + u];
      Bs[lc][lu0+u] = A[(size_t)(k0+lc)*NNODE + w0 + lu0 + u];
    }
    __syncthreads();
    for (int u = 0; u < 32; ++u){
      float bw = Bs[u][tx];
      #pragma unroll
      for (int j = 0; j < 4; ++j) acc[j] += As[tyg + 8*j][u] * bw;
    }
  }
  __syncthreads();
  #pragma unroll
  for (int j = 0; j < 4; ++j) Cs[tyg + 8*j][tx] = acc[j];   // Cs[v_local][w_local]
  __syncthreads();
  for (int i = tid; i < 1024; i += 256){
    int wl = i >> 5, vl = i & 31;
    supT[((size_t)(2*which+1)*NNODE + w0 + wl)*NNODE + v0 + vl] = f2bf(Cs[vl][wl]);
  }
}

// ---------------- x0 = start conv on left-padded input ----------------
__global__ void k_make_x0(const float* __restrict__ input, const float* __restrict__ start_w,
                          const float* __restrict__ start_b, float* __restrict__ x0){
  int idx = blockIdx.x*256 + threadIdx.x;
  const int total = BB*RFP*CCH*NNODE;
  if (idx >= total) return;
  int n = idx & 511;
  int rest = idx >> 9;
  int c = rest & 31; rest >>= 5;
  int t = rest % RFP;
  int b = rest / RFP;
  float v = (t == 0) ? 0.f : input[((size_t)b*TIN + (t-1))*NNODE + n];
  x0[idx] = start_w[c] * v + start_b[c];
}

// ---------------- dilated conv + tanh*sigmoid gate -> bf16 act ----------------
__global__ __launch_bounds__(256) void k_dconv_act(const float* __restrict__ x,
      const float* __restrict__ fw, const float* __restrict__ fb,
      const float* __restrict__ gw, const float* __restrict__ gb,
      unsigned short* __restrict__ out, int Tin, int Tp, int dil){
  int n0 = blockIdx.x * 64;
  int t = blockIdx.y;
  int b = blockIdx.z;
  int tid = threadIdx.x;
  int lane = tid & 63, cg = tid >> 6;
  __shared__ float X0[32][64], X1[32][64];
  __shared__ float fwl[32][32][2], gwl[32][32][2];
  const float* xb0 = x + ((size_t)(b*Tin + t)*CCH)*NNODE;
  const float* xb1 = x + ((size_t)(b*Tin + t + dil)*CCH)*NNODE;
  for (int i = tid; i < 32*64; i += 256){
    int c = i >> 6, nn2 = i & 63;
    X0[c][nn2] = xb0[c*NNODE + n0 + nn2];
    X1[c][nn2] = xb1[c*NNODE + n0 + nn2];
  }
  for (int i = tid; i < 2048; i += 256){
    ((float*)fwl)[i] = fw[i];
    ((float*)gwl)[i] = gw[i];
  }
  __syncthreads();
  float F[8], G[8];
  #pragma unroll
  for (int j = 0; j < 8; ++j){ int c = cg*8 + j; F[j] = fb[c]; G[j] = gb[c]; }
  for (int cp = 0; cp < 32; ++cp){
    float x0v = X0[cp][lane], x1v = X1[cp][lane];
    #pragma unroll
    for (int j = 0; j < 8; ++j){
      int c = cg*8 + j;
      F[j] += x0v * fwl[c][cp][0] + x1v * fwl[c][cp][1];
      G[j] += x0v * gwl[c][cp][0] + x1v * gwl[c][cp][1];
    }
  }
  unsigned short* ob = out + ((size_t)(b*Tp + t)*CCH)*NNODE;
  #pragma unroll
  for (int j = 0; j < 8; ++j){
    int c = cg*8 + j;
    ob[c*NNODE + n0 + lane] = f2bf(tanhf(F[j]) * sigmoidf_(G[j]));
  }
}

// ---------------- skip accumulation at last time slice (bf16 act) ----------------
__global__ __launch_bounds__(256) void k_skip_accum(const unsigned short* __restrict__ act,
     const float* __restrict__ sw, const float* __restrict__ sb,
     float* __restrict__ skip, int Tp){
  int n0 = blockIdx.x * 64;
  int e0 = blockIdx.y * 32;
  int b = blockIdx.z;
  int tid = threadIdx.x;
  int lane = tid & 63, eg = tid >> 6;
  __shared__ float Xs[32][64];
  const unsigned short* ab = act + ((size_t)(b*Tp + Tp-1)*CCH)*NNODE;
  for (int i = tid; i < 2048; i += 256){
    int c = i >> 6, nn2 = i & 63;
    Xs[c][nn2] = bf2f(ab[c*NNODE + n0 + nn2]);
  }
  __syncthreads();
  float acc[8];
  #pragma unroll
  for (int j = 0; j < 8; ++j) acc[j] = sb[e0 + eg*8 + j];
  for (int c = 0; c < 32; ++c){
    float xv = Xs[c][lane];
    #pragma unroll
    for (int j = 0; j < 8; ++j) acc[j] += sw[(e0 + eg*8 + j)*CCH + c] * xv;
  }
  #pragma unroll
  for (int j = 0; j < 8; ++j){
    int e = e0 + eg*8 + j;
    skip[((size_t)b*SKC + e)*NNODE + n0 + lane] += acc[j];
  }
}

// ---------------- bf16 MFMA GEMM: Y[m, (s,n)] = A[m, v] * BT[(s,n), v] ----------------
__global__ __launch_bounds__(256) void k_gemm(
    const unsigned short* __restrict__ A, const unsigned short* __restrict__ BT,
    unsigned short* __restrict__ Y, int Mb, long long bStride){
  __shared__ short As[64][64];
  __shared__ short Bs[128][64];
  int tid = threadIdx.x;
  int n0 = blockIdx.x * 128;
  int rowBase = blockIdx.z * Mb + blockIdx.y * 64;
  int rowEnd  = blockIdx.z * Mb + Mb;
  const unsigned short* Bb = BT + (size_t)blockIdx.z * bStride;
  int wid = tid >> 6, lane = tid & 63;
  int wm = wid >> 1, wn = wid & 1;
  int l15 = lane & 15, l4 = lane >> 4;
  f32x4 acc[2][4];
  #pragma unroll
  for (int mf = 0; mf < 2; ++mf)
    #pragma unroll
    for (int nf = 0; nf < 4; ++nf)
      acc[mf][nf] = (f32x4){0.f, 0.f, 0.f, 0.f};
  for (int k0 = 0; k0 < 512; k0 += 64){
    __syncthreads();
    #pragma unroll
    for (int it = 0; it < 2; ++it){
      int r = it*32 + (tid>>3), g = tid & 7;
      int arow = rowBase + r;
      int4 v = {0,0,0,0};
      if (arow < rowEnd)
        v = *(const int4*)(A + (size_t)arow*512 + k0 + g*8);
      *(int4*)&As[r][((g ^ (r&7)) << 3)] = v;
    }
    #pragma unroll
    for (int it = 0; it < 4; ++it){
      int r = it*32 + (tid>>3), g = tid & 7;
      int4 v = *(const int4*)(Bb + (size_t)(n0 + r)*512 + k0 + g*8);
      *(int4*)&Bs[r][((g ^ (r&7)) << 3)] = v;
    }
    __syncthreads();
    #pragma unroll
    for (int ks = 0; ks < 2; ++ks){
      bf16x8 af[2], bfr[4];
      #pragma unroll
      for (int mf = 0; mf < 2; ++mf){
        int r = wm*32 + mf*16 + l15;
        af[mf] = *(const bf16x8*)&As[r][(((ks*4 + l4) ^ (r & 7)) << 3)];
      }
      #pragma unroll
      for (int nf = 0; nf < 4; ++nf){
        int r = wn*64 + nf*16 + l15;
        bfr[nf] = *(const bf16x8*)&Bs[r][(((ks*4 + l4) ^ (r & 7)) << 3)];
      }
      #pragma unroll
      for (int mf = 0; mf < 2; ++mf)
        #pragma unroll
        for (int nf = 0; nf < 4; ++nf)
          acc[mf][nf] = __builtin_amdgcn_mfma_f32_16x16x32_bf16(af[mf], bfr[nf], acc[mf][nf], 0, 0, 0);
    }
  }
  #pragma unroll
  for (int mf = 0; mf < 2; ++mf){
    #pragma unroll
    for (int nf = 0; nf < 4; ++nf){
      #pragma unroll
      for (int r = 0; r < 4; ++r){
        int row = rowBase + wm*32 + mf*16 + l4*4 + r;
        if (row < rowEnd){
          int col = n0 + wn*64 + nf*16 + l15;
          Y[(size_t)row*2048 + col] = f2bf(acc[mf][nf][r]);
        }
      }
    }
  }
}

// ---------------- channel mix: out = bias + Wx*g0 + sum_s Ws*Y_s (+res,bn) ----------------
__global__ __launch_bounds__(256) void k_mix(
    const unsigned short* __restrict__ g0in, const unsigned short* __restrict__ Y,
    const float* __restrict__ w, const float* __restrict__ bias,
    unsigned short* outBf,
    float* __restrict__ outF, const float* __restrict__ res,
    const float* __restrict__ bng, const float* __restrict__ bnb,
    int Tp, int dil){
  int bt = blockIdx.x;
  int n = blockIdx.y*256 + threadIdx.x;
  float acc[32];
  #pragma unroll
  for (int o = 0; o < 32; ++o) acc[o] = bias[o];
  const unsigned short* g0r = g0in + (size_t)bt*32*512 + n;
  const unsigned short* yr  = Y + (size_t)bt*32*2048 + n;
  for (int c = 0; c < 32; ++c){
    float v = bf2f(g0r[(size_t)c*512]);
    #pragma unroll
    for (int o = 0; o < 32; ++o) acc[o] += w[o*160 + c] * v;
  }
  for (int s = 0; s < 4; ++s){
    for (int c = 0; c < 32; ++c){
      float v = bf2f(yr[(size_t)c*2048 + s*512]);
      #pragma unroll
      for (int o = 0; o < 32; ++o) acc[o] += w[o*160 + 32 + s*32 + c] * v;
    }
  }
  if (outF){
    int b = bt / Tp, t = bt - b*Tp;
    const float* rb = res + ((size_t)(b*(Tp+dil) + t + dil)*32)*512 + n;
    const float inv = 1.0f / sqrtf(1.0f + 1e-5f);
    float* ob = outF + (size_t)bt*32*512 + n;
    #pragma unroll
    for (int o = 0; o < 32; ++o){
      float x = acc[o] + rb[(size_t)o*512];
      ob[(size_t)o*512] = x * (bng[o]*inv) + bnb[o];
    }
  } else {
    unsigned short* ob = outBf + (size_t)bt*32*512 + n;
    #pragma unroll
    for (int o = 0; o < 32; ++o) ob[(size_t)o*512] = f2bf(acc[o]);
  }
}

// ---------------- end MLP: relu(skip) -> relu(end1) -> end2 ----------------
__global__ __launch_bounds__(256) void k_end(const float* __restrict__ skip,
    const float* __restrict__ e1w, const float* __restrict__ e1b,
    const float* __restrict__ e2w, const float* __restrict__ e2b,
    float* __restrict__ out){
  int n0 = blockIdx.x * 16;
  int b = blockIdx.y;
  int tid = threadIdx.x;
  __shared__ float sk[SKC][17];
  __shared__ float hid[ENDC][17];
  for (int i = tid; i < SKC*16; i += 256){
    int s = i >> 4, nn2 = i & 15;
    float v = skip[((size_t)b*SKC + s)*NNODE + n0 + nn2];
    sk[s][nn2] = v > 0.f ? v : 0.f;
  }
  __syncthreads();
  for (int i = tid; i < ENDC*16; i += 256){
    int e = i >> 4, nn2 = i & 15;
    float a = e1b[e];
    for (int s = 0; s < SKC; ++s) a += e1w[e*SKC + s] * sk[s][nn2];
    hid[e][nn2] = a > 0.f ? a : 0.f;
  }
  __syncthreads();
  if (tid < ODIM*16){
    int o = tid >> 4, nn2 = tid & 15;
    float a = e2b[o];
    for (int e = 0; e < ENDC; ++e) a += e2w[o*ENDC + e] * hid[e][nn2];
    out[((size_t)b*ODIM + o)*NNODE + n0 + nn2] = a;
  }
}

extern "C" void kernel_launch(void* const* d_in, const int* in_sizes, int n_in,
                              void* d_out, int out_size, void* d_ws, size_t ws_size,
                              hipStream_t stream){
  const float* input   = (const float*)d_in[0];
  const float* supports= (const float*)d_in[1];
  const float* emb     = (const float*)d_in[2];
  const float* embds_w = (const float*)d_in[3];
  const float* embds_b = (const float*)d_in[4];
  const float* wl_w    = (const float*)d_in[5];
  const float* wl_b    = (const float*)d_in[6];
  const float* wr_w    = (const float*)d_in[7];
  const float* wr_b    = (const float*)d_in[8];
  const float* start_w = (const float*)d_in[9];
  const float* start_b = (const float*)d_in[10];
  const float* filter_w= (const float*)d_in[11];
  const float* filter_b= (const float*)d_in[12];
  const float* gate_w  = (const float*)d_in[13];
  const float* gate_b  = (const float*)d_in[14];
  const float* skip_w  = (const float*)d_in[15];
  const float* skip_b  = (const float*)d_in[16];
  const float* bn_g    = (const float*)d_in[17];
  const float* bn_b    = (const float*)d_in[18];
  const float* gconv_w = (const float*)d_in[19];
  const float* gconv_b = (const float*)d_in[20];
  const float* dyn_w   = (const float*)d_in[21];
  const float* dyn_b   = (const float*)d_in[22];
  const float* end1_w  = (const float*)d_in[23];
  const float* end1_b  = (const float*)d_in[24];
  const float* end2_w  = (const float*)d_in[25];
  const float* end2_b  = (const float*)d_in[26];
  float* out = (float*)d_out;

  float* ws = (float*)d_ws;
  // ---- Region R0: 33,554,432 floats. Prologue: fp32 att/dyn. Loop phase:
  //      act | bufP | bufQ | skip | Y  (sums to exactly 33,554,432 floats).
  float* dyn = ws;
  unsigned short* act = (unsigned short*)ws;                 // 3,145,728 floats
  float* bufP = ws + 3145728;                                // 6,815,744
  float* bufQ = ws + 3145728 + 6815744;                      // 6,815,744
  float* skip = ws + 16777216;                               // 4,194,304
  unsigned short* Y = (unsigned short*)(ws + 20971520);      // 12,582,912 floats
  // ---- dynT region: 16,777,216 floats (33,554,432 bf16). Prologue alias: l/r.
  unsigned short* dynT = (unsigned short*)(ws + 33554432);
  float* lbuf = ws + 33554432;                               // 2,097,152 (alias)
  float* rbuf = ws + 33554432 + 2097152;                     // 2,097,152 (alias)
  // ---- supT: 524,288 floats. Total ws use: 50,855,936 floats = 203.4 MB.
  unsigned short* supT = (unsigned short*)(ws + 33554432 + 16777216);

  hipLaunchKernelGGL(k_feat_lr, dim3(BB*NNODE), dim3(128), 0, stream,
                     input, emb, embds_w, embds_b, wl_w, wl_b, wr_w, wr_b, lbuf, rbuf);
  hipLaunchKernelGGL(k_att, dim3(16, 16, BB*NH), dim3(256), 0, stream, lbuf, rbuf, dyn);
  hipLaunchKernelGGL(k_topk_softmax, dim3(BB*NH*NNODE), dim3(256), 0, stream, dyn);
  hipLaunchKernelGGL(k_transpose_dyn, dim3(8, 8, BB*NH), dim3(256), 0, stream, dyn, dynT);
  hipLaunchKernelGGL(k_supT_copy, dim3(8, 8, 2), dim3(256), 0, stream, supports, supT);
  hipLaunchKernelGGL(k_supT_sq, dim3(16, 16, 2), dim3(256), 0, stream, supports, supT);
  {
    int total = BB*RFP*CCH*NNODE;
    hipLaunchKernelGGL(k_make_x0, dim3((total+255)/256), dim3(256), 0, stream,
                       input, start_w, start_b, bufP);
  }
  {
    int n = BB*SKC*NNODE;
    hipLaunchKernelGGL(k_zero, dim3((n+255)/256), dim3(256), 0, stream, skip, n);
  }

  const int dil_[8] = {1,2,1,2,1,2,1,2};
  int T = RFP;
  float* P = bufP; float* Q = bufQ;
  for (int i = 0; i < NL; ++i){
    int d = dil_[i], Tp = T - d;
    int Mb = Tp*32;
    hipLaunchKernelGGL(k_dconv_act, dim3(8, Tp, BB), dim3(256), 0, stream,
        P, filter_w + i*2048, filter_b + i*32, gate_w + i*2048, gate_b + i*32,
        act, T, Tp, d);
    hipLaunchKernelGGL(k_skip_accum, dim3(8, 8, BB), dim3(256), 0, stream,
        act, skip_w + i*SKC*CCH, skip_b + i*SKC, skip, Tp);
    // dyn GCN: Y = act * dynT(b), then mix -> act (in place)
    hipLaunchKernelGGL(k_gemm, dim3(16, (Mb+63)/64, BB), dim3(256), 0, stream,
        act, dynT, Y, Mb, (long long)NH*NNODE*NNODE);
    hipLaunchKernelGGL(k_mix, dim3(BB*Tp, 2), dim3(256), 0, stream,
        act, Y, dyn_w + i*5120, dyn_b + i*32,
        act, (float*)nullptr, (const float*)nullptr, (const float*)nullptr,
        (const float*)nullptr, Tp, d);
    // sup GCN: Y = act * supT, then mix (+residual+bn) -> Q fp32
    hipLaunchKernelGGL(k_gemm, dim3(16, (Mb+63)/64, BB), dim3(256), 0, stream,
        act, supT, Y, Mb, 0LL);
    hipLaunchKernelGGL(k_mix, dim3(BB*Tp, 2), dim3(256), 0, stream,
        act, Y, gconv_w + i*5120, gconv_b + i*32,
        (unsigned short*)nullptr, Q, P, bn_g + i*32, bn_b + i*32, Tp, d);
    float* tmp = P; P = Q; Q = tmp;
    T = Tp;
  }
  hipLaunchKernelGGL(k_end, dim3(NNODE/16, BB), dim3(256), 0, stream,
                     skip, end1_w, end1_b, end2_w, end2_b, out);
}

// Round 5
// 2498.264 us; speedup vs baseline: 3.1991x; 1.1314x over previous
//
#include <hip/hip_runtime.h>
#include <math.h>

#define BB 32
#define NNODE 512
#define TIN 12
#define CCH 32
#define NH 4
#define DDIM 32
#define NL 8
#define SKC 256
#define ENDC 512
#define ODIM 12
#define RFP 13

typedef __attribute__((ext_vector_type(8))) short bf16x8;
typedef __attribute__((ext_vector_type(4))) float f32x4;

__device__ __forceinline__ float sigmoidf_(float x){ return 1.0f/(1.0f+expf(-x)); }
__device__ __forceinline__ unsigned short f2bf(float f){
  unsigned u = __float_as_uint(f);
  u += 0x7FFFu + ((u >> 16) & 1u);
  return (unsigned short)(u >> 16);
}
__device__ __forceinline__ float bf2f(unsigned short h){
  return __uint_as_float(((unsigned)h) << 16);
}
__device__ __forceinline__ void gload16(const void* g, void* l){
  __builtin_amdgcn_global_load_lds(
      (const __attribute__((address_space(1))) void*)g,
      (__attribute__((address_space(3))) void*)l, 16, 0, 0);
}

// ---------------- zero fill ----------------
__global__ void k_zero(float* __restrict__ p, int n){
  int i = blockIdx.x*256 + threadIdx.x;
  if (i < n) p[i] = 0.f;
}

// ---------------- feature -> l, r ----------------
__global__ void k_feat_lr(const float* __restrict__ input, const float* __restrict__ emb,
                          const float* __restrict__ embds_w, const float* __restrict__ embds_b,
                          const float* __restrict__ wl_w, const float* __restrict__ wl_b,
                          const float* __restrict__ wr_w, const float* __restrict__ wr_b,
                          float* __restrict__ lbuf, float* __restrict__ rbuf){
  int bn = blockIdx.x;          // b*N + n
  int b = bn >> 9, n = bn & 511;
  int j = threadIdx.x;          // 0..127
  __shared__ float f[TIN];
  if (j < TIN){
    float s = 0.f;
    for (int t = 0; t < TIN; ++t) s += input[(b*TIN + t)*NNODE + n] * embds_w[t];
    f[j] = s + embds_b[0] + emb[n*TIN + j];
  }
  __syncthreads();
  float lv = wl_b[j], rv = wr_b[j];
  for (int t = 0; t < TIN; ++t){
    float ft = f[t];
    lv += ft * wl_w[t*128 + j];
    rv += ft * wr_w[t*128 + j];
  }
  int h = j >> 5, d = j & 31;
  int o = ((b*NH + h)*NNODE + n)*DDIM + d;
  lbuf[o] = lv; rbuf[o] = rv;
}

// ---------------- att = l r^T / sqrt(32), 32x32 tiles ----------------
__global__ __launch_bounds__(256) void k_att(const float* __restrict__ lbuf,
                      const float* __restrict__ rbuf, float* __restrict__ att){
  int bh = blockIdx.z;
  int n0 = blockIdx.y * 32, m0 = blockIdx.x * 32;
  int tid = threadIdx.x;
  int tx = tid & 31, ty = tid >> 5;   // 8 row-groups
  __shared__ float Ls[32][33], Rs[32][33];
  const float* lb = lbuf + (size_t)bh*NNODE*DDIM;
  const float* rb = rbuf + (size_t)bh*NNODE*DDIM;
  for (int i = tid; i < 1024; i += 256){
    int r = i >> 5, c = i & 31;
    Ls[r][c] = lb[(n0+r)*DDIM + c];
    Rs[r][c] = rb[(m0+r)*DDIM + c];
  }
  __syncthreads();
  float acc[4] = {0.f,0.f,0.f,0.f};
  for (int d = 0; d < 32; ++d){
    float rv = Rs[tx][d];
    #pragma unroll
    for (int j = 0; j < 4; ++j) acc[j] += Ls[ty + 8*j][d] * rv;
  }
  #pragma unroll
  for (int j = 0; j < 4; ++j)
    att[((size_t)bh*NNODE + n0+ty+8*j)*NNODE + m0 + tx] = acc[j] / sqrtf(32.0f);
}

// ---------------- per-row exact top-k (radix select, wave-scan) + softmax ----------------
__global__ __launch_bounds__(256) void k_topk_softmax(float* __restrict__ att){
  int row = blockIdx.x;                 // (b*H + h)*N + n
  int h = (row >> 9) & 3;
  int k = (h==0)?10:(h==1)?20:(h==2)?40:500;
  float* rp = att + (size_t)row * NNODE;
  __shared__ unsigned uv[NNODE];
  __shared__ int hist[256];
  __shared__ int redc[4];
  __shared__ unsigned s_pfx;
  __shared__ int s_kr;
  __shared__ float redm[4], reds[4];
  int tid = threadIdx.x;
  int lane = tid & 63, w = tid >> 6;
  float v0 = rp[tid], v1 = rp[tid+256];
  unsigned a0 = __float_as_uint(v0); a0 = (a0 & 0x80000000u) ? ~a0 : (a0 | 0x80000000u);
  unsigned a1 = __float_as_uint(v1); a1 = (a1 & 0x80000000u) ? ~a1 : (a1 | 0x80000000u);
  uv[tid] = a0; uv[tid+256] = a1;
  float m = fmaxf(v0, v1);
  for (int off = 32; off; off >>= 1) m = fmaxf(m, __shfl_down(m, off, 64));
  if (lane == 0) redm[w] = m;
  if (tid == 0){ s_kr = k; s_pfx = 0u; }
  __syncthreads();
  float mx = fmaxf(fmaxf(redm[0], redm[1]), fmaxf(redm[2], redm[3]));
  for (int rnd = 0; rnd < 4; ++rnd){
    int sh = 24 - rnd*8;
    hist[tid] = 0;
    __syncthreads();
    unsigned pfx = s_pfx;
    int kr = s_kr;
    bool c0 = (rnd == 0) || ((a0 >> (sh+8)) == (pfx >> (sh+8)));
    bool c1 = (rnd == 0) || ((a1 >> (sh+8)) == (pfx >> (sh+8)));
    if (c0) atomicAdd(&hist[(a0 >> sh) & 255], 1);
    if (c1) atomicAdd(&hist[(a1 >> sh) & 255], 1);
    __syncthreads();
    int h_own = hist[tid];
    int s = h_own;
    #pragma unroll
    for (int off = 1; off < 64; off <<= 1){
      int y = __shfl_down(s, off, 64);
      if (lane + off < 64) s += y;
    }
    if (lane == 0) redc[w] = s;
    __syncthreads();
    int addW = 0;
    for (int w2 = w+1; w2 < 4; ++w2) addW += redc[w2];
    int scv = s + addW;              // inclusive suffix count for bins >= tid
    if (scv >= kr && (scv - h_own) < kr){
      s_kr = kr - (scv - h_own);
      s_pfx = pfx | ((unsigned)tid << sh);
    }
    __syncthreads();
  }
  unsigned uth = s_pfx;
  int neq = s_kr;     // ties kept, lowest index first
  float e0 = 0.f, e1 = 0.f;
  {
    bool keep = a0 > uth;
    if (!keep && a0 == uth){
      int rank = 0;
      for (int j = 0; j < tid; ++j) rank += (uv[j] == uth);
      keep = rank < neq;
    }
    if (keep) e0 = expf(v0 - mx);
  }
  {
    int i = tid + 256;
    bool keep = a1 > uth;
    if (!keep && a1 == uth){
      int rank = 0;
      for (int j = 0; j < i; ++j) rank += (uv[j] == uth);
      keep = rank < neq;
    }
    if (keep) e1 = expf(v1 - mx);
  }
  float s = e0 + e1;
  for (int off = 32; off; off >>= 1) s += __shfl_down(s, off, 64);
  if (lane == 0) reds[w] = s;
  __syncthreads();
  float tot = reds[0] + reds[1] + reds[2] + reds[3];
  rp[tid] = e0 / tot;
  rp[tid + 256] = e1 / tot;
}

// ---------------- transpose dyn (fp32 [bs][v][w]) -> dynT (bf16 [bs][w][v]) ----------------
__global__ __launch_bounds__(256) void k_transpose_dyn(const float* __restrict__ dyn,
                                                       unsigned short* __restrict__ dynT){
  int bs = blockIdx.z;
  int v0 = blockIdx.x*64, w0 = blockIdx.y*64;
  __shared__ float Ts[64][65];
  const float* S = dyn + (size_t)bs*NNODE*NNODE;
  unsigned short* D = dynT + (size_t)bs*NNODE*NNODE;
  int tid = threadIdx.x;
  for (int i = tid; i < 4096; i += 256){
    int r = i >> 6, c = i & 63;
    Ts[r][c] = S[(size_t)(v0+r)*NNODE + w0 + c];
  }
  __syncthreads();
  for (int i = tid; i < 4096; i += 256){
    int r = i >> 6, c = i & 63;
    D[(size_t)(w0+r)*NNODE + v0 + c] = f2bf(Ts[c][r]);
  }
}

// ---------------- supT: transpose s0, s1 into blocks 0, 2 ----------------
__global__ __launch_bounds__(256) void k_supT_copy(const float* __restrict__ supports,
                                                   unsigned short* __restrict__ supT){
  int w = blockIdx.z;                  // 0 -> s0 (block 0), 1 -> s1 (block 2)
  int v0 = blockIdx.x*64, n0 = blockIdx.y*64;
  __shared__ float Ts[64][65];
  const float* S = supports + (size_t)w*NNODE*NNODE;
  int tid = threadIdx.x;
  for (int i = tid; i < 4096; i += 256){
    int r = i >> 6, c = i & 63;
    Ts[r][c] = S[(size_t)(v0+r)*NNODE + n0 + c];
  }
  __syncthreads();
  for (int i = tid; i < 4096; i += 256){
    int r = i >> 6, c = i & 63;
    supT[((size_t)(2*w)*NNODE + n0 + r)*NNODE + v0 + c] = f2bf(Ts[c][r]);
  }
}

// ---------------- supT squares: s@s, transposed store into blocks 1, 3 ----------------
__global__ __launch_bounds__(256) void k_supT_sq(const float* __restrict__ supports,
                                                 unsigned short* __restrict__ supT){
  int which = blockIdx.z;              // 0 -> s0^2 (block 1), 1 -> s1^2 (block 3)
  const float* A = supports + (size_t)which*NNODE*NNODE;
  int w0 = blockIdx.x * 32, v0 = blockIdx.y * 32;
  int tid = threadIdx.x;
  int tx = tid & 31, tyg = tid >> 5;
  __shared__ float As[32][33], Bs[32][33], Cs[32][33];
  float acc[4] = {0.f,0.f,0.f,0.f};
  for (int k0 = 0; k0 < NNODE; k0 += 32){
    int lc = tid >> 3, lu0 = (tid & 7) * 4;
    __syncthreads();
    for (int u = 0; u < 4; ++u){
      As[lc][lu0+u] = A[(size_t)(v0+lc)*NNODE + k0 + lu0 + u];
      Bs[lc][lu0+u] = A[(size_t)(k0+lc)*NNODE + w0 + lu0 + u];
    }
    __syncthreads();
    for (int u = 0; u < 32; ++u){
      float bw = Bs[u][tx];
      #pragma unroll
      for (int j = 0; j < 4; ++j) acc[j] += As[tyg + 8*j][u] * bw;
    }
  }
  __syncthreads();
  #pragma unroll
  for (int j = 0; j < 4; ++j) Cs[tyg + 8*j][tx] = acc[j];   // Cs[v_local][w_local]
  __syncthreads();
  for (int i = tid; i < 1024; i += 256){
    int wl = i >> 5, vl = i & 31;
    supT[((size_t)(2*which+1)*NNODE + w0 + wl)*NNODE + v0 + vl] = f2bf(Cs[vl][wl]);
  }
}

// ---------------- x0 = start conv on left-padded input ----------------
__global__ void k_make_x0(const float* __restrict__ input, const float* __restrict__ start_w,
                          const float* __restrict__ start_b, float* __restrict__ x0){
  int idx = blockIdx.x*256 + threadIdx.x;
  const int total = BB*RFP*CCH*NNODE;
  if (idx >= total) return;
  int n = idx & 511;
  int rest = idx >> 9;
  int c = rest & 31; rest >>= 5;
  int t = rest % RFP;
  int b = rest / RFP;
  float v = (t == 0) ? 0.f : input[((size_t)b*TIN + (t-1))*NNODE + n];
  x0[idx] = start_w[c] * v + start_b[c];
}

// ---------------- dilated conv + tanh*sigmoid gate -> bf16 act ----------------
__global__ __launch_bounds__(256) void k_dconv_act(const float* __restrict__ x,
      const float* __restrict__ fw, const float* __restrict__ fb,
      const float* __restrict__ gw, const float* __restrict__ gb,
      unsigned short* __restrict__ out, int Tin, int Tp, int dil){
  int n0 = blockIdx.x * 64;
  int t = blockIdx.y;
  int b = blockIdx.z;
  int tid = threadIdx.x;
  int lane = tid & 63, cg = tid >> 6;
  __shared__ float X0[32][64], X1[32][64];
  __shared__ float fwl[32][32][2], gwl[32][32][2];
  const float* xb0 = x + ((size_t)(b*Tin + t)*CCH)*NNODE;
  const float* xb1 = x + ((size_t)(b*Tin + t + dil)*CCH)*NNODE;
  for (int i = tid; i < 32*64; i += 256){
    int c = i >> 6, nn2 = i & 63;
    X0[c][nn2] = xb0[c*NNODE + n0 + nn2];
    X1[c][nn2] = xb1[c*NNODE + n0 + nn2];
  }
  for (int i = tid; i < 2048; i += 256){
    ((float*)fwl)[i] = fw[i];
    ((float*)gwl)[i] = gw[i];
  }
  __syncthreads();
  float F[8], G[8];
  #pragma unroll
  for (int j = 0; j < 8; ++j){ int c = cg*8 + j; F[j] = fb[c]; G[j] = gb[c]; }
  for (int cp = 0; cp < 32; ++cp){
    float x0v = X0[cp][lane], x1v = X1[cp][lane];
    #pragma unroll
    for (int j = 0; j < 8; ++j){
      int c = cg*8 + j;
      F[j] += x0v * fwl[c][cp][0] + x1v * fwl[c][cp][1];
      G[j] += x0v * gwl[c][cp][0] + x1v * gwl[c][cp][1];
    }
  }
  unsigned short* ob = out + ((size_t)(b*Tp + t)*CCH)*NNODE;
  #pragma unroll
  for (int j = 0; j < 8; ++j){
    int c = cg*8 + j;
    ob[c*NNODE + n0 + lane] = f2bf(tanhf(F[j]) * sigmoidf_(G[j]));
  }
}

// ---------------- skip accumulation at last time slice (bf16 act) ----------------
__global__ __launch_bounds__(256) void k_skip_accum(const unsigned short* __restrict__ act,
     const float* __restrict__ sw, const float* __restrict__ sb,
     float* __restrict__ skip, int Tp){
  int n0 = blockIdx.x * 64;
  int e0 = blockIdx.y * 32;
  int b = blockIdx.z;
  int tid = threadIdx.x;
  int lane = tid & 63, eg = tid >> 6;
  __shared__ float Xs[32][64];
  const unsigned short* ab = act + ((size_t)(b*Tp + Tp-1)*CCH)*NNODE;
  for (int i = tid; i < 2048; i += 256){
    int c = i >> 6, nn2 = i & 63;
    Xs[c][nn2] = bf2f(ab[c*NNODE + n0 + nn2]);
  }
  __syncthreads();
  float acc[8];
  #pragma unroll
  for (int j = 0; j < 8; ++j) acc[j] = sb[e0 + eg*8 + j];
  for (int c = 0; c < 32; ++c){
    float xv = Xs[c][lane];
    #pragma unroll
    for (int j = 0; j < 8; ++j) acc[j] += sw[(e0 + eg*8 + j)*CCH + c] * xv;
  }
  #pragma unroll
  for (int j = 0; j < 8; ++j){
    int e = e0 + eg*8 + j;
    skip[((size_t)b*SKC + e)*NNODE + n0 + lane] += acc[j];
  }
}

// ---------------- bf16 MFMA GEMM: Y[m, n] = A[m, v] * BT[n, v] (generic K) ----------------
__global__ __launch_bounds__(256) void k_gemm(
    const unsigned short* __restrict__ A, const unsigned short* __restrict__ BT,
    unsigned short* __restrict__ Y, int Mb, long long bStride,
    int K, int Ystride, int relu){
  __shared__ short As[64][64];
  __shared__ short Bs[128][64];
  int tid = threadIdx.x;
  int n0 = blockIdx.x * 128;
  int rowBase = blockIdx.z * Mb + blockIdx.y * 64;
  int rowEnd  = blockIdx.z * Mb + Mb;
  const unsigned short* Bb = BT + (size_t)blockIdx.z * bStride;
  int wid = tid >> 6, lane = tid & 63;
  int wm = wid >> 1, wn = wid & 1;
  int l15 = lane & 15, l4 = lane >> 4;
  f32x4 acc[2][4];
  #pragma unroll
  for (int mf = 0; mf < 2; ++mf)
    #pragma unroll
    for (int nf = 0; nf < 4; ++nf)
      acc[mf][nf] = (f32x4){0.f, 0.f, 0.f, 0.f};
  for (int k0 = 0; k0 < K; k0 += 64){
    __syncthreads();
    // async global->LDS, source column pre-swizzled, LDS dest linear (rule #21)
    #pragma unroll
    for (int it = 0; it < 2; ++it){
      int r = it*32 + (tid>>3), g = tid & 7;
      gload16(A + (size_t)(rowBase + r)*K + k0 + ((g ^ (r&7))<<3), &As[r][g<<3]);
    }
    #pragma unroll
    for (int it = 0; it < 4; ++it){
      int r = it*32 + (tid>>3), g = tid & 7;
      gload16(Bb + (size_t)(n0 + r)*K + k0 + ((g ^ (r&7))<<3), &Bs[r][g<<3]);
    }
    __syncthreads();
    #pragma unroll
    for (int ks = 0; ks < 2; ++ks){
      bf16x8 af[2], bfr[4];
      #pragma unroll
      for (int mf = 0; mf < 2; ++mf){
        int r = wm*32 + mf*16 + l15;
        af[mf] = *(const bf16x8*)&As[r][(((ks*4 + l4) ^ (r & 7)) << 3)];
      }
      #pragma unroll
      for (int nf = 0; nf < 4; ++nf){
        int r = wn*64 + nf*16 + l15;
        bfr[nf] = *(const bf16x8*)&Bs[r][(((ks*4 + l4) ^ (r & 7)) << 3)];
      }
      #pragma unroll
      for (int mf = 0; mf < 2; ++mf)
        #pragma unroll
        for (int nf = 0; nf < 4; ++nf)
          acc[mf][nf] = __builtin_amdgcn_mfma_f32_16x16x32_bf16(af[mf], bfr[nf], acc[mf][nf], 0, 0, 0);
    }
  }
  #pragma unroll
  for (int mf = 0; mf < 2; ++mf){
    #pragma unroll
    for (int nf = 0; nf < 4; ++nf){
      #pragma unroll
      for (int r = 0; r < 4; ++r){
        int row = rowBase + wm*32 + mf*16 + l4*4 + r;
        if (row < rowEnd){
          int col = n0 + wn*64 + nf*16 + l15;
          float v = acc[mf][nf][r];
          if (relu) v = v > 0.f ? v : 0.f;
          Y[(size_t)row*Ystride + col] = f2bf(v);
        }
      }
    }
  }
}

// ---------------- channel mix: out = bias + Wx*g0 + sum_s Ws*Y_s (+res,bn) ----------------
__global__ __launch_bounds__(256) void k_mix(
    const unsigned short* __restrict__ g0in, const unsigned short* __restrict__ Y,
    const float* __restrict__ w, const float* __restrict__ bias,
    unsigned short* outBf,
    float* __restrict__ outF, const float* __restrict__ res,
    const float* __restrict__ bng, const float* __restrict__ bnb,
    int Tp, int dil){
  int bt = blockIdx.x;
  int n = blockIdx.y*256 + threadIdx.x;
  float acc[32];
  #pragma unroll
  for (int o = 0; o < 32; ++o) acc[o] = bias[o];
  const unsigned short* g0r = g0in + (size_t)bt*32*512 + n;
  const unsigned short* yr  = Y + (size_t)bt*32*2048 + n;
  for (int c = 0; c < 32; ++c){
    float v = bf2f(g0r[(size_t)c*512]);
    #pragma unroll
    for (int o = 0; o < 32; ++o) acc[o] += w[o*160 + c] * v;
  }
  for (int s = 0; s < 4; ++s){
    for (int c = 0; c < 32; ++c){
      float v = bf2f(yr[(size_t)c*2048 + s*512]);
      #pragma unroll
      for (int o = 0; o < 32; ++o) acc[o] += w[o*160 + 32 + s*32 + c] * v;
    }
  }
  if (outF){
    int b = bt / Tp, t = bt - b*Tp;
    const float* rb = res + ((size_t)(b*(Tp+dil) + t + dil)*32)*512 + n;
    const float inv = 1.0f / sqrtf(1.0f + 1e-5f);
    float* ob = outF + (size_t)bt*32*512 + n;
    #pragma unroll
    for (int o = 0; o < 32; ++o){
      float x = acc[o] + rb[(size_t)o*512];
      ob[(size_t)o*512] = x * (bng[o]*inv) + bnb[o];
    }
  } else {
    unsigned short* ob = outBf + (size_t)bt*32*512 + n;
    #pragma unroll
    for (int o = 0; o < 32; ++o) ob[(size_t)o*512] = f2bf(acc[o]);
  }
}

// ---------------- skip -> relu -> bf16 transposed [(b,n), e] ----------------
__global__ __launch_bounds__(256) void k_skipT(const float* __restrict__ skip,
                                               unsigned short* __restrict__ skT){
  int b = blockIdx.z, e0 = blockIdx.y*64, n0 = blockIdx.x*64;
  __shared__ float Ts[64][65];
  int tid = threadIdx.x;
  for (int i = tid; i < 4096; i += 256){
    int r = i >> 6, c = i & 63;
    Ts[r][c] = skip[((size_t)b*SKC + e0 + r)*NNODE + n0 + c];
  }
  __syncthreads();
  for (int i = tid; i < 4096; i += 256){
    int r = i >> 6, c = i & 63;     // r = n-local, c = e-local
    float v = Ts[c][r];
    skT[((size_t)b*NNODE + n0 + r)*SKC + e0 + c] = f2bf(v > 0.f ? v : 0.f);
  }
}

// ---------------- fp32 -> bf16 weight converts ----------------
__global__ void k_cvt(const float* __restrict__ src, unsigned short* __restrict__ dst, int n){
  int i = blockIdx.x*256 + threadIdx.x;
  if (i < n) dst[i] = f2bf(src[i]);
}
__global__ void k_cvt_e2(const float* __restrict__ e2w, unsigned short* __restrict__ dst){
  int i = blockIdx.x*256 + threadIdx.x;   // 16*512
  if (i < 16*ENDC){
    int o = i >> 9;
    dst[i] = (o < ODIM) ? f2bf(e2w[(size_t)o*ENDC + (i & 511)]) : (unsigned short)0;
  }
}

// ---------------- end2: out[b,o,n] = e2b[o] + hid[(b,n),:]·e2w[o,:] ----------------
__global__ __launch_bounds__(256) void k_end2(const unsigned short* __restrict__ hid,
    const unsigned short* __restrict__ e2wB, const float* __restrict__ e2b,
    float* __restrict__ out){
  int rowBase = blockIdx.x * 64;
  int tid = threadIdx.x;
  int lane = tid & 63, w = tid >> 6;
  int l15 = lane & 15, l4 = lane >> 4;
  __shared__ unsigned short e2s[16][520];
  __shared__ float Cs[16][68];
  for (int i = tid; i < 4096; i += 256){
    int r = i >> 8, c2 = (i & 255) * 2;
    *(unsigned*)&e2s[r][c2] = *(const unsigned*)&e2wB[(size_t)r*ENDC + c2];
  }
  __syncthreads();
  f32x4 acc = (f32x4){0.f,0.f,0.f,0.f};
  const unsigned short* Ab = hid + (size_t)(rowBase + w*16 + l15)*ENDC;
  #pragma unroll
  for (int kk = 0; kk < 16; ++kk){
    bf16x8 af = *(const bf16x8*)(Ab + kk*32 + l4*8);
    bf16x8 bf = *(const bf16x8*)&e2s[l15][kk*32 + l4*8];
    acc = __builtin_amdgcn_mfma_f32_16x16x32_bf16(af, bf, acc, 0, 0, 0);
  }
  #pragma unroll
  for (int r = 0; r < 4; ++r)
    Cs[l15][w*16 + l4*4 + r] = acc[r];
  __syncthreads();
  for (int i = tid; i < ODIM*64; i += 256){
    int o = i >> 6, nl = i & 63;
    int gr = rowBase + nl;
    int b = gr >> 9, n = gr & 511;
    out[((size_t)(b*ODIM + o))*NNODE + n] = Cs[o][nl] + e2b[o];
  }
}

extern "C" void kernel_launch(void* const* d_in, const int* in_sizes, int n_in,
                              void* d_out, int out_size, void* d_ws, size_t ws_size,
                              hipStream_t stream){
  const float* input   = (const float*)d_in[0];
  const float* supports= (const float*)d_in[1];
  const float* emb     = (const float*)d_in[2];
  const float* embds_w = (const float*)d_in[3];
  const float* embds_b = (const float*)d_in[4];
  const float* wl_w    = (const float*)d_in[5];
  const float* wl_b    = (const float*)d_in[6];
  const float* wr_w    = (const float*)d_in[7];
  const float* wr_b    = (const float*)d_in[8];
  const float* start_w = (const float*)d_in[9];
  const float* start_b = (const float*)d_in[10];
  const float* filter_w= (const float*)d_in[11];
  const float* filter_b= (const float*)d_in[12];
  const float* gate_w  = (const float*)d_in[13];
  const float* gate_b  = (const float*)d_in[14];
  const float* skip_w  = (const float*)d_in[15];
  const float* skip_b  = (const float*)d_in[16];
  const float* bn_g    = (const float*)d_in[17];
  const float* bn_b    = (const float*)d_in[18];
  const float* gconv_w = (const float*)d_in[19];
  const float* gconv_b = (const float*)d_in[20];
  const float* dyn_w   = (const float*)d_in[21];
  const float* dyn_b   = (const float*)d_in[22];
  const float* end1_w  = (const float*)d_in[23];
  const float* end1_b  = (const float*)d_in[24];
  const float* end2_w  = (const float*)d_in[25];
  const float* end2_b  = (const float*)d_in[26];
  float* out = (float*)d_out;

  float* ws = (float*)d_ws;
  // ---- Region R0: 33,554,432 floats. Prologue: fp32 att/dyn. Loop phase:
  //      act | bufP | bufQ | skip | Y  (sums to exactly 33,554,432 floats).
  float* dyn = ws;
  unsigned short* act = (unsigned short*)ws;                 // 3,145,728 floats
  float* bufP = ws + 3145728;                                // 6,815,744
  float* bufQ = ws + 3145728 + 6815744;                      // 6,815,744
  float* skip = ws + 16777216;                               // 4,194,304
  unsigned short* Y = (unsigned short*)(ws + 20971520);      // 12,582,912 floats
  // ---- dynT region: 16,777,216 floats (33,554,432 bf16). Prologue alias: l/r.
  unsigned short* dynT = (unsigned short*)(ws + 33554432);
  float* lbuf = ws + 33554432;                               // 2,097,152 (alias)
  float* rbuf = ws + 33554432 + 2097152;                     // 2,097,152 (alias)
  // ---- supT: 524,288 floats.
  unsigned short* supT = (unsigned short*)(ws + 33554432 + 16777216);
  // ---- end-MLP buffers (used only after the layer loop):
  unsigned short* skT  = (unsigned short*)(ws + 50855936);   // 2,097,152 floats
  unsigned short* hid  = (unsigned short*)(ws + 52953088);   // 4,194,304 floats
  unsigned short* e1wB = (unsigned short*)(ws + 57147392);   //    65,536 floats
  unsigned short* e2wB = (unsigned short*)(ws + 57212928);   //     4,096 floats
  // total: 57,217,024 floats = 228.9 MB (< 237 MB proven-safe)

  hipLaunchKernelGGL(k_feat_lr, dim3(BB*NNODE), dim3(128), 0, stream,
                     input, emb, embds_w, embds_b, wl_w, wl_b, wr_w, wr_b, lbuf, rbuf);
  hipLaunchKernelGGL(k_att, dim3(16, 16, BB*NH), dim3(256), 0, stream, lbuf, rbuf, dyn);
  hipLaunchKernelGGL(k_topk_softmax, dim3(BB*NH*NNODE), dim3(256), 0, stream, dyn);
  hipLaunchKernelGGL(k_transpose_dyn, dim3(8, 8, BB*NH), dim3(256), 0, stream, dyn, dynT);
  hipLaunchKernelGGL(k_supT_copy, dim3(8, 8, 2), dim3(256), 0, stream, supports, supT);
  hipLaunchKernelGGL(k_supT_sq, dim3(16, 16, 2), dim3(256), 0, stream, supports, supT);
  {
    int total = BB*RFP*CCH*NNODE;
    hipLaunchKernelGGL(k_make_x0, dim3((total+255)/256), dim3(256), 0, stream,
                       input, start_w, start_b, bufP);
  }
  {
    int n = BB*SKC*NNODE;
    hipLaunchKernelGGL(k_zero, dim3((n+255)/256), dim3(256), 0, stream, skip, n);
  }

  const int dil_[8] = {1,2,1,2,1,2,1,2};
  int T = RFP;
  float* P = bufP; float* Q = bufQ;
  for (int i = 0; i < NL; ++i){
    int d = dil_[i], Tp = T - d;
    int Mb = Tp*32;
    hipLaunchKernelGGL(k_dconv_act, dim3(8, Tp, BB), dim3(256), 0, stream,
        P, filter_w + i*2048, filter_b + i*32, gate_w + i*2048, gate_b + i*32,
        act, T, Tp, d);
    hipLaunchKernelGGL(k_skip_accum, dim3(8, 8, BB), dim3(256), 0, stream,
        act, skip_w + i*SKC*CCH, skip_b + i*SKC, skip, Tp);
    // dyn GCN: Y = act * dynT(b), then mix -> act (in place)
    hipLaunchKernelGGL(k_gemm, dim3(16, (Mb+63)/64, BB), dim3(256), 0, stream,
        act, dynT, Y, Mb, (long long)NH*NNODE*NNODE, 512, 2048, 0);
    hipLaunchKernelGGL(k_mix, dim3(BB*Tp, 2), dim3(256), 0, stream,
        act, Y, dyn_w + i*5120, dyn_b + i*32,
        act, (float*)nullptr, (const float*)nullptr, (const float*)nullptr,
        (const float*)nullptr, Tp, d);
    // sup GCN: Y = act * supT, then mix (+residual+bn) -> Q fp32
    hipLaunchKernelGGL(k_gemm, dim3(16, (Mb+63)/64, BB), dim3(256), 0, stream,
        act, supT, Y, Mb, 0LL, 512, 2048, 0);
    hipLaunchKernelGGL(k_mix, dim3(BB*Tp, 2), dim3(256), 0, stream,
        act, Y, gconv_w + i*5120, gconv_b + i*32,
        (unsigned short*)nullptr, Q, P, bn_g + i*32, bn_b + i*32, Tp, d);
    float* tmp = P; P = Q; Q = tmp;
    T = Tp;
  }
  // ---- end MLP: skipT -> MFMA end1 (relu) -> MFMA end2 ----
  hipLaunchKernelGGL(k_skipT, dim3(8, 4, BB), dim3(256), 0, stream, skip, skT);
  hipLaunchKernelGGL(k_cvt, dim3((ENDC*SKC+255)/256), dim3(256), 0, stream,
                     end1_w, e1wB, ENDC*SKC);
  hipLaunchKernelGGL(k_cvt_e2, dim3((16*ENDC+255)/256), dim3(256), 0, stream,
                     end2_w, e2wB);
  hipLaunchKernelGGL(k_gemm, dim3(4, 256, 1), dim3(256), 0, stream,
      skT, e1wB, hid, BB*NNODE, 0LL, 256, 512, 1);
  hipLaunchKernelGGL(k_end2, dim3(256), dim3(256), 0, stream, hid, e2wB, end1_b, out);
}

// Round 6
// 2350.352 us; speedup vs baseline: 3.4004x; 1.0629x over previous
//
#include <hip/hip_runtime.h>
#include <math.h>

#define BB 32
#define NNODE 512
#define TIN 12
#define CCH 32
#define NH 4
#define DDIM 32
#define NL 8
#define SKC 256
#define ENDC 512
#define ODIM 12
#define RFP 13

typedef __attribute__((ext_vector_type(8))) short bf16x8;
typedef __attribute__((ext_vector_type(4))) float f32x4;

__device__ __forceinline__ float sigmoidf_(float x){ return 1.0f/(1.0f+expf(-x)); }
__device__ __forceinline__ unsigned short f2bf(float f){
  unsigned u = __float_as_uint(f);
  u += 0x7FFFu + ((u >> 16) & 1u);
  return (unsigned short)(u >> 16);
}
__device__ __forceinline__ float bf2f(unsigned short h){
  return __uint_as_float(((unsigned)h) << 16);
}
__device__ __forceinline__ void gload16(const void* g, void* l){
  __builtin_amdgcn_global_load_lds(
      (const __attribute__((address_space(1))) void*)g,
      (__attribute__((address_space(3))) void*)l, 16, 0, 0);
}

// ---------------- zero fill ----------------
__global__ void k_zero(float* __restrict__ p, int n){
  int i = blockIdx.x*256 + threadIdx.x;
  if (i < n) p[i] = 0.f;
}

// ---------------- feature -> l, r ----------------
__global__ void k_feat_lr(const float* __restrict__ input, const float* __restrict__ emb,
                          const float* __restrict__ embds_w, const float* __restrict__ embds_b,
                          const float* __restrict__ wl_w, const float* __restrict__ wl_b,
                          const float* __restrict__ wr_w, const float* __restrict__ wr_b,
                          float* __restrict__ lbuf, float* __restrict__ rbuf){
  int bn = blockIdx.x;          // b*N + n
  int b = bn >> 9, n = bn & 511;
  int j = threadIdx.x;          // 0..127
  __shared__ float f[TIN];
  if (j < TIN){
    float s = 0.f;
    for (int t = 0; t < TIN; ++t) s += input[(b*TIN + t)*NNODE + n] * embds_w[t];
    f[j] = s + embds_b[0] + emb[n*TIN + j];
  }
  __syncthreads();
  float lv = wl_b[j], rv = wr_b[j];
  for (int t = 0; t < TIN; ++t){
    float ft = f[t];
    lv += ft * wl_w[t*128 + j];
    rv += ft * wr_w[t*128 + j];
  }
  int h = j >> 5, d = j & 31;
  int o = ((b*NH + h)*NNODE + n)*DDIM + d;
  lbuf[o] = lv; rbuf[o] = rv;
}

// ---------------- att = l r^T / sqrt(32), 32x32 tiles ----------------
__global__ __launch_bounds__(256) void k_att(const float* __restrict__ lbuf,
                      const float* __restrict__ rbuf, float* __restrict__ att){
  int bh = blockIdx.z;
  int n0 = blockIdx.y * 32, m0 = blockIdx.x * 32;
  int tid = threadIdx.x;
  int tx = tid & 31, ty = tid >> 5;   // 8 row-groups
  __shared__ float Ls[32][33], Rs[32][33];
  const float* lb = lbuf + (size_t)bh*NNODE*DDIM;
  const float* rb = rbuf + (size_t)bh*NNODE*DDIM;
  for (int i = tid; i < 1024; i += 256){
    int r = i >> 5, c = i & 31;
    Ls[r][c] = lb[(n0+r)*DDIM + c];
    Rs[r][c] = rb[(m0+r)*DDIM + c];
  }
  __syncthreads();
  float acc[4] = {0.f,0.f,0.f,0.f};
  for (int d = 0; d < 32; ++d){
    float rv = Rs[tx][d];
    #pragma unroll
    for (int j = 0; j < 4; ++j) acc[j] += Ls[ty + 8*j][d] * rv;
  }
  #pragma unroll
  for (int j = 0; j < 4; ++j)
    att[((size_t)bh*NNODE + n0+ty+8*j)*NNODE + m0 + tx] = acc[j] / sqrtf(32.0f);
}

// -------- per-row exact top-k (radix select, wave-scan) + softmax; bf16 out in place --------
__global__ __launch_bounds__(256) void k_topk_softmax(float* __restrict__ att){
  int row = blockIdx.x;                 // (b*H + h)*N + n
  int h = (row >> 9) & 3;
  int k = (h==0)?10:(h==1)?20:(h==2)?40:500;
  float* rp = att + (size_t)row * NNODE;
  __shared__ unsigned uv[NNODE];
  __shared__ int hist[256];
  __shared__ int redc[4];
  __shared__ unsigned s_pfx;
  __shared__ int s_kr;
  __shared__ float redm[4], reds[4];
  int tid = threadIdx.x;
  int lane = tid & 63, w = tid >> 6;
  float v0 = rp[tid], v1 = rp[tid+256];
  unsigned a0 = __float_as_uint(v0); a0 = (a0 & 0x80000000u) ? ~a0 : (a0 | 0x80000000u);
  unsigned a1 = __float_as_uint(v1); a1 = (a1 & 0x80000000u) ? ~a1 : (a1 | 0x80000000u);
  uv[tid] = a0; uv[tid+256] = a1;
  float m = fmaxf(v0, v1);
  for (int off = 32; off; off >>= 1) m = fmaxf(m, __shfl_down(m, off, 64));
  if (lane == 0) redm[w] = m;
  if (tid == 0){ s_kr = k; s_pfx = 0u; }
  __syncthreads();
  float mx = fmaxf(fmaxf(redm[0], redm[1]), fmaxf(redm[2], redm[3]));
  for (int rnd = 0; rnd < 4; ++rnd){
    int sh = 24 - rnd*8;
    hist[tid] = 0;
    __syncthreads();
    unsigned pfx = s_pfx;
    int kr = s_kr;
    bool c0 = (rnd == 0) || ((a0 >> (sh+8)) == (pfx >> (sh+8)));
    bool c1 = (rnd == 0) || ((a1 >> (sh+8)) == (pfx >> (sh+8)));
    if (c0) atomicAdd(&hist[(a0 >> sh) & 255], 1);
    if (c1) atomicAdd(&hist[(a1 >> sh) & 255], 1);
    __syncthreads();
    int h_own = hist[tid];
    int s = h_own;
    #pragma unroll
    for (int off = 1; off < 64; off <<= 1){
      int y = __shfl_down(s, off, 64);
      if (lane + off < 64) s += y;
    }
    if (lane == 0) redc[w] = s;
    __syncthreads();
    int addW = 0;
    for (int w2 = w+1; w2 < 4; ++w2) addW += redc[w2];
    int scv = s + addW;              // inclusive suffix count for bins >= tid
    if (scv >= kr && (scv - h_own) < kr){
      s_kr = kr - (scv - h_own);
      s_pfx = pfx | ((unsigned)tid << sh);
    }
    __syncthreads();
  }
  unsigned uth = s_pfx;
  int neq = s_kr;     // ties kept, lowest index first
  float e0 = 0.f, e1 = 0.f;
  {
    bool keep = a0 > uth;
    if (!keep && a0 == uth){
      int rank = 0;
      for (int j = 0; j < tid; ++j) rank += (uv[j] == uth);
      keep = rank < neq;
    }
    if (keep) e0 = expf(v0 - mx);
  }
  {
    int i = tid + 256;
    bool keep = a1 > uth;
    if (!keep && a1 == uth){
      int rank = 0;
      for (int j = 0; j < i; ++j) rank += (uv[j] == uth);
      keep = rank < neq;
    }
    if (keep) e1 = expf(v1 - mx);
  }
  float s = e0 + e1;
  for (int off = 32; off; off >>= 1) s += __shfl_down(s, off, 64);
  if (lane == 0) reds[w] = s;
  __syncthreads();
  float tot = reds[0] + reds[1] + reds[2] + reds[3];
  // write bf16 probs in place (row's short-view; all reads completed long ago)
  unsigned short* rp16 = (unsigned short*)rp;
  rp16[tid] = f2bf(e0 / tot);
  rp16[tid + 256] = f2bf(e1 / tot);
}

// ------- transpose dynBf (bf16 rows, stride 1024 shorts) -> dynT (bf16 [bs][w][v]) -------
__global__ __launch_bounds__(256) void k_transpose_dyn(const unsigned short* __restrict__ dynBf,
                                                       unsigned short* __restrict__ dynT){
  int bs = blockIdx.z;
  int v0 = blockIdx.x*64, w0 = blockIdx.y*64;
  __shared__ unsigned short Ts[64][66];
  const unsigned short* S = dynBf + (size_t)bs*NNODE*1024;
  unsigned short* D = dynT + (size_t)bs*NNODE*NNODE;
  int tid = threadIdx.x;
  for (int i = tid; i < 4096; i += 256){
    int r = i >> 6, c = i & 63;
    Ts[r][c] = S[(size_t)(v0+r)*1024 + w0 + c];
  }
  __syncthreads();
  for (int i = tid; i < 4096; i += 256){
    int r = i >> 6, c = i & 63;
    D[(size_t)(w0+r)*NNODE + v0 + c] = Ts[c][r];
  }
}

// ---------------- supT: transpose s0, s1 into blocks 0, 2 ----------------
__global__ __launch_bounds__(256) void k_supT_copy(const float* __restrict__ supports,
                                                   unsigned short* __restrict__ supT){
  int w = blockIdx.z;                  // 0 -> s0 (block 0), 1 -> s1 (block 2)
  int v0 = blockIdx.x*64, n0 = blockIdx.y*64;
  __shared__ float Ts[64][65];
  const float* S = supports + (size_t)w*NNODE*NNODE;
  int tid = threadIdx.x;
  for (int i = tid; i < 4096; i += 256){
    int r = i >> 6, c = i & 63;
    Ts[r][c] = S[(size_t)(v0+r)*NNODE + n0 + c];
  }
  __syncthreads();
  for (int i = tid; i < 4096; i += 256){
    int r = i >> 6, c = i & 63;
    supT[((size_t)(2*w)*NNODE + n0 + r)*NNODE + v0 + c] = f2bf(Ts[c][r]);
  }
}

// ---------------- supT squares: s@s, transposed store into blocks 1, 3 ----------------
__global__ __launch_bounds__(256) void k_supT_sq(const float* __restrict__ supports,
                                                 unsigned short* __restrict__ supT){
  int which = blockIdx.z;              // 0 -> s0^2 (block 1), 1 -> s1^2 (block 3)
  const float* A = supports + (size_t)which*NNODE*NNODE;
  int w0 = blockIdx.x * 32, v0 = blockIdx.y * 32;
  int tid = threadIdx.x;
  int tx = tid & 31, tyg = tid >> 5;
  __shared__ float As[32][33], Bs[32][33], Cs[32][33];
  float acc[4] = {0.f,0.f,0.f,0.f};
  for (int k0 = 0; k0 < NNODE; k0 += 32){
    int lc = tid >> 3, lu0 = (tid & 7) * 4;
    __syncthreads();
    for (int u = 0; u < 4; ++u){
      As[lc][lu0+u] = A[(size_t)(v0+lc)*NNODE + k0 + lu0 + u];
      Bs[lc][lu0+u] = A[(size_t)(k0+lc)*NNODE + w0 + lu0 + u];
    }
    __syncthreads();
    for (int u = 0; u < 32; ++u){
      float bw = Bs[u][tx];
      #pragma unroll
      for (int j = 0; j < 4; ++j) acc[j] += As[tyg + 8*j][u] * bw;
    }
  }
  __syncthreads();
  #pragma unroll
  for (int j = 0; j < 4; ++j) Cs[tyg + 8*j][tx] = acc[j];   // Cs[v_local][w_local]
  __syncthreads();
  for (int i = tid; i < 1024; i += 256){
    int wl = i >> 5, vl = i & 31;
    supT[((size_t)(2*which+1)*NNODE + w0 + wl)*NNODE + v0 + vl] = f2bf(Cs[vl][wl]);
  }
}

// ---------------- x0 = start conv on left-padded input ----------------
__global__ void k_make_x0(const float* __restrict__ input, const float* __restrict__ start_w,
                          const float* __restrict__ start_b, float* __restrict__ x0){
  int idx = blockIdx.x*256 + threadIdx.x;
  const int total = BB*RFP*CCH*NNODE;
  if (idx >= total) return;
  int n = idx & 511;
  int rest = idx >> 9;
  int c = rest & 31; rest >>= 5;
  int t = rest % RFP;
  int b = rest / RFP;
  float v = (t == 0) ? 0.f : input[((size_t)b*TIN + (t-1))*NNODE + n];
  x0[idx] = start_w[c] * v + start_b[c];
}

// ---------------- dilated conv + tanh*sigmoid gate -> bf16 act ----------------
__global__ __launch_bounds__(256) void k_dconv_act(const float* __restrict__ x,
      const float* __restrict__ fw, const float* __restrict__ fb,
      const float* __restrict__ gw, const float* __restrict__ gb,
      unsigned short* __restrict__ out, int Tin, int Tp, int dil){
  int n0 = blockIdx.x * 64;
  int t = blockIdx.y;
  int b = blockIdx.z;
  int tid = threadIdx.x;
  int lane = tid & 63, cg = tid >> 6;
  __shared__ float X0[32][64], X1[32][64];
  __shared__ float fwl[32][32][2], gwl[32][32][2];
  const float* xb0 = x + ((size_t)(b*Tin + t)*CCH)*NNODE;
  const float* xb1 = x + ((size_t)(b*Tin + t + dil)*CCH)*NNODE;
  for (int i = tid; i < 32*64; i += 256){
    int c = i >> 6, nn2 = i & 63;
    X0[c][nn2] = xb0[c*NNODE + n0 + nn2];
    X1[c][nn2] = xb1[c*NNODE + n0 + nn2];
  }
  for (int i = tid; i < 2048; i += 256){
    ((float*)fwl)[i] = fw[i];
    ((float*)gwl)[i] = gw[i];
  }
  __syncthreads();
  float F[8], G[8];
  #pragma unroll
  for (int j = 0; j < 8; ++j){ int c = cg*8 + j; F[j] = fb[c]; G[j] = gb[c]; }
  for (int cp = 0; cp < 32; ++cp){
    float x0v = X0[cp][lane], x1v = X1[cp][lane];
    #pragma unroll
    for (int j = 0; j < 8; ++j){
      int c = cg*8 + j;
      F[j] += x0v * fwl[c][cp][0] + x1v * fwl[c][cp][1];
      G[j] += x0v * gwl[c][cp][0] + x1v * gwl[c][cp][1];
    }
  }
  unsigned short* ob = out + ((size_t)(b*Tp + t)*CCH)*NNODE;
  #pragma unroll
  for (int j = 0; j < 8; ++j){
    int c = cg*8 + j;
    ob[c*NNODE + n0 + lane] = f2bf(tanhf(F[j]) * sigmoidf_(G[j]));
  }
}

// ---------------- skip accumulation at last time slice (bf16 act) ----------------
__global__ __launch_bounds__(256) void k_skip_accum(const unsigned short* __restrict__ act,
     const float* __restrict__ sw, const float* __restrict__ sb,
     float* __restrict__ skip, int Tp){
  int n0 = blockIdx.x * 64;
  int e0 = blockIdx.y * 32;
  int b = blockIdx.z;
  int tid = threadIdx.x;
  int lane = tid & 63, eg = tid >> 6;
  __shared__ float Xs[32][64];
  const unsigned short* ab = act + ((size_t)(b*Tp + Tp-1)*CCH)*NNODE;
  for (int i = tid; i < 2048; i += 256){
    int c = i >> 6, nn2 = i & 63;
    Xs[c][nn2] = bf2f(ab[c*NNODE + n0 + nn2]);
  }
  __syncthreads();
  float acc[8];
  #pragma unroll
  for (int j = 0; j < 8; ++j) acc[j] = sb[e0 + eg*8 + j];
  for (int c = 0; c < 32; ++c){
    float xv = Xs[c][lane];
    #pragma unroll
    for (int j = 0; j < 8; ++j) acc[j] += sw[(e0 + eg*8 + j)*CCH + c] * xv;
  }
  #pragma unroll
  for (int j = 0; j < 8; ++j){
    int e = e0 + eg*8 + j;
    skip[((size_t)b*SKC + e)*NNODE + n0 + lane] += acc[j];
  }
}

// ------- bf16 MFMA GEMM, 128x128 tile: Y[m, n] = A[m, v] * BT[n, v] (generic K) -------
__global__ __launch_bounds__(256) void k_gemm(
    const unsigned short* __restrict__ A, const unsigned short* __restrict__ BT,
    unsigned short* __restrict__ Y, int Mb, long long bStride,
    int K, int Ystride, int relu){
  __shared__ short As[128][64];
  __shared__ short Bs[128][64];
  int tid = threadIdx.x;
  int n0 = blockIdx.x * 128;
  int rowBase = blockIdx.z * Mb + blockIdx.y * 128;
  int rowEnd  = blockIdx.z * Mb + Mb;
  const unsigned short* Bb = BT + (size_t)blockIdx.z * bStride;
  int wid = tid >> 6, lane = tid & 63;
  int wm = wid >> 1, wn = wid & 1;
  int l15 = lane & 15, l4 = lane >> 4;
  f32x4 acc[4][4];
  #pragma unroll
  for (int mf = 0; mf < 4; ++mf)
    #pragma unroll
    for (int nf = 0; nf < 4; ++nf)
      acc[mf][nf] = (f32x4){0.f, 0.f, 0.f, 0.f};
  for (int k0 = 0; k0 < K; k0 += 64){
    __syncthreads();
    // async global->LDS; source column pre-swizzled, LDS dest linear (rule #21)
    #pragma unroll
    for (int it = 0; it < 4; ++it){
      int r = it*32 + (tid>>3), g = tid & 7;
      gload16(A + (size_t)(rowBase + r)*K + k0 + ((g ^ (r&7))<<3), &As[r][g<<3]);
      gload16(Bb + (size_t)(n0 + r)*K + k0 + ((g ^ (r&7))<<3), &Bs[r][g<<3]);
    }
    __syncthreads();
    #pragma unroll
    for (int ks = 0; ks < 2; ++ks){
      bf16x8 af[4], bfr[4];
      #pragma unroll
      for (int mf = 0; mf < 4; ++mf){
        int r = wm*64 + mf*16 + l15;
        af[mf] = *(const bf16x8*)&As[r][(((ks*4 + l4) ^ (r & 7)) << 3)];
      }
      #pragma unroll
      for (int nf = 0; nf < 4; ++nf){
        int r = wn*64 + nf*16 + l15;
        bfr[nf] = *(const bf16x8*)&Bs[r][(((ks*4 + l4) ^ (r & 7)) << 3)];
      }
      #pragma unroll
      for (int mf = 0; mf < 4; ++mf)
        #pragma unroll
        for (int nf = 0; nf < 4; ++nf)
          acc[mf][nf] = __builtin_amdgcn_mfma_f32_16x16x32_bf16(af[mf], bfr[nf], acc[mf][nf], 0, 0, 0);
    }
  }
  #pragma unroll
  for (int mf = 0; mf < 4; ++mf){
    #pragma unroll
    for (int nf = 0; nf < 4; ++nf){
      #pragma unroll
      for (int r = 0; r < 4; ++r){
        int row = rowBase + wm*64 + mf*16 + l4*4 + r;
        if (row < rowEnd){
          int col = n0 + wn*64 + nf*16 + l15;
          float v = acc[mf][nf][r];
          if (relu) v = v > 0.f ? v : 0.f;
          Y[(size_t)row*Ystride + col] = f2bf(v);
        }
      }
    }
  }
}

// ------- channel mix (FMA-bound): out = bias + Wx*g0 + sum_s Ws*Y_s (+res,bn) -------
__global__ __launch_bounds__(256) void k_mix(
    const unsigned short* __restrict__ g0in, const unsigned short* __restrict__ Y,
    const float* __restrict__ w, const float* __restrict__ bias,
    unsigned short* outBf,
    float* __restrict__ outF, const float* __restrict__ res,
    const float* __restrict__ bng, const float* __restrict__ bnb,
    int Tp, int dil){
  int bt = blockIdx.x;
  int tid = threadIdx.x;
  int n = tid << 1;                       // 2 nodes per thread
  __shared__ float wl[5120];              // wl[c*32+o] = w[o*160+c]
  for (int i = tid; i < 5120; i += 256){
    int c = i >> 5, o = i & 31;
    wl[i] = w[o*160 + c];
  }
  __syncthreads();
  float a0[32], a1[32];
  #pragma unroll
  for (int o = 0; o < 32; ++o){ float bv = bias[o]; a0[o] = bv; a1[o] = bv; }
  const unsigned short* g0r = g0in + (size_t)bt*32*512 + n;
  const unsigned short* yr  = Y + (size_t)bt*32*2048 + n;
  for (int c = 0; c < 32; ++c){
    unsigned u = *(const unsigned*)(g0r + (size_t)c*512);
    float v0 = bf2f((unsigned short)(u & 0xffffu));
    float v1 = bf2f((unsigned short)(u >> 16));
    const float* wc = wl + c*32;
    #pragma unroll
    for (int o = 0; o < 32; o += 4){
      float4 wv = *(const float4*)(wc + o);
      a0[o  ] += wv.x*v0; a1[o  ] += wv.x*v1;
      a0[o+1] += wv.y*v0; a1[o+1] += wv.y*v1;
      a0[o+2] += wv.z*v0; a1[o+2] += wv.z*v1;
      a0[o+3] += wv.w*v0; a1[o+3] += wv.w*v1;
    }
  }
  #pragma unroll
  for (int s = 0; s < 4; ++s){
    for (int c = 0; c < 32; ++c){
      unsigned u = *(const unsigned*)(yr + (size_t)(c*2048 + s*512));
      float v0 = bf2f((unsigned short)(u & 0xffffu));
      float v1 = bf2f((unsigned short)(u >> 16));
      const float* wc = wl + (32 + s*32 + c)*32;
      #pragma unroll
      for (int o = 0; o < 32; o += 4){
        float4 wv = *(const float4*)(wc + o);
        a0[o  ] += wv.x*v0; a1[o  ] += wv.x*v1;
        a0[o+1] += wv.y*v0; a1[o+1] += wv.y*v1;
        a0[o+2] += wv.z*v0; a1[o+2] += wv.z*v1;
        a0[o+3] += wv.w*v0; a1[o+3] += wv.w*v1;
      }
    }
  }
  if (outF){
    int b = bt / Tp, t = bt - b*Tp;
    const float* rb = res + ((size_t)(b*(Tp+dil) + t + dil)*32)*512 + n;
    const float inv = 1.0f / sqrtf(1.0f + 1e-5f);
    float* ob = outF + (size_t)bt*32*512 + n;
    #pragma unroll
    for (int o = 0; o < 32; ++o){
      float2 rv = *(const float2*)(rb + (size_t)o*512);
      float g = bng[o]*inv, b2 = bnb[o];
      float2 ov;
      ov.x = (a0[o] + rv.x) * g + b2;
      ov.y = (a1[o] + rv.y) * g + b2;
      *(float2*)(ob + (size_t)o*512) = ov;
    }
  } else {
    unsigned short* ob = outBf + (size_t)bt*32*512 + n;
    #pragma unroll
    for (int o = 0; o < 32; ++o){
      unsigned pk = (unsigned)f2bf(a0[o]) | ((unsigned)f2bf(a1[o]) << 16);
      *(unsigned*)(ob + (size_t)o*512) = pk;
    }
  }
}

// ---------------- skip -> relu -> bf16 transposed [(b,n), e] ----------------
__global__ __launch_bounds__(256) void k_skipT(const float* __restrict__ skip,
                                               unsigned short* __restrict__ skT){
  int b = blockIdx.z, e0 = blockIdx.y*64, n0 = blockIdx.x*64;
  __shared__ float Ts[64][65];
  int tid = threadIdx.x;
  for (int i = tid; i < 4096; i += 256){
    int r = i >> 6, c = i & 63;
    Ts[r][c] = skip[((size_t)b*SKC + e0 + r)*NNODE + n0 + c];
  }
  __syncthreads();
  for (int i = tid; i < 4096; i += 256){
    int r = i >> 6, c = i & 63;     // r = n-local, c = e-local
    float v = Ts[c][r];
    skT[((size_t)b*NNODE + n0 + r)*SKC + e0 + c] = f2bf(v > 0.f ? v : 0.f);
  }
}

// ---------------- fp32 -> bf16 weight converts ----------------
__global__ void k_cvt(const float* __restrict__ src, unsigned short* __restrict__ dst, int n){
  int i = blockIdx.x*256 + threadIdx.x;
  if (i < n) dst[i] = f2bf(src[i]);
}
__global__ void k_cvt_e2(const float* __restrict__ e2w, unsigned short* __restrict__ dst){
  int i = blockIdx.x*256 + threadIdx.x;   // 16*512
  if (i < 16*ENDC){
    int o = i >> 9;
    dst[i] = (o < ODIM) ? f2bf(e2w[(size_t)o*ENDC + (i & 511)]) : (unsigned short)0;
  }
}

// ---------------- end2: out[b,o,n] = e2b[o] + hid[(b,n),:]·e2w[o,:] ----------------
__global__ __launch_bounds__(256) void k_end2(const unsigned short* __restrict__ hid,
    const unsigned short* __restrict__ e2wB, const float* __restrict__ e2b,
    float* __restrict__ out){
  int rowBase = blockIdx.x * 64;
  int tid = threadIdx.x;
  int lane = tid & 63, w = tid >> 6;
  int l15 = lane & 15, l4 = lane >> 4;
  __shared__ unsigned short e2s[16][520];
  __shared__ float Cs[16][68];
  for (int i = tid; i < 4096; i += 256){
    int r = i >> 8, c2 = (i & 255) * 2;
    *(unsigned*)&e2s[r][c2] = *(const unsigned*)&e2wB[(size_t)r*ENDC + c2];
  }
  __syncthreads();
  f32x4 acc = (f32x4){0.f,0.f,0.f,0.f};
  const unsigned short* Ab = hid + (size_t)(rowBase + w*16 + l15)*ENDC;
  #pragma unroll
  for (int kk = 0; kk < 16; ++kk){
    bf16x8 af = *(const bf16x8*)(Ab + kk*32 + l4*8);
    bf16x8 bf = *(const bf16x8*)&e2s[l15][kk*32 + l4*8];
    acc = __builtin_amdgcn_mfma_f32_16x16x32_bf16(af, bf, acc, 0, 0, 0);
  }
  #pragma unroll
  for (int r = 0; r < 4; ++r)
    Cs[l15][w*16 + l4*4 + r] = acc[r];
  __syncthreads();
  for (int i = tid; i < ODIM*64; i += 256){
    int o = i >> 6, nl = i & 63;
    int gr = rowBase + nl;
    int b = gr >> 9, n = gr & 511;
    out[((size_t)(b*ODIM + o))*NNODE + n] = Cs[o][nl] + e2b[o];
  }
}

extern "C" void kernel_launch(void* const* d_in, const int* in_sizes, int n_in,
                              void* d_out, int out_size, void* d_ws, size_t ws_size,
                              hipStream_t stream){
  const float* input   = (const float*)d_in[0];
  const float* supports= (const float*)d_in[1];
  const float* emb     = (const float*)d_in[2];
  const float* embds_w = (const float*)d_in[3];
  const float* embds_b = (const float*)d_in[4];
  const float* wl_w    = (const float*)d_in[5];
  const float* wl_b    = (const float*)d_in[6];
  const float* wr_w    = (const float*)d_in[7];
  const float* wr_b    = (const float*)d_in[8];
  const float* start_w = (const float*)d_in[9];
  const float* start_b = (const float*)d_in[10];
  const float* filter_w= (const float*)d_in[11];
  const float* filter_b= (const float*)d_in[12];
  const float* gate_w  = (const float*)d_in[13];
  const float* gate_b  = (const float*)d_in[14];
  const float* skip_w  = (const float*)d_in[15];
  const float* skip_b  = (const float*)d_in[16];
  const float* bn_g    = (const float*)d_in[17];
  const float* bn_b    = (const float*)d_in[18];
  const float* gconv_w = (const float*)d_in[19];
  const float* gconv_b = (const float*)d_in[20];
  const float* dyn_w   = (const float*)d_in[21];
  const float* dyn_b   = (const float*)d_in[22];
  const float* end1_w  = (const float*)d_in[23];
  const float* end1_b  = (const float*)d_in[24];
  const float* end2_w  = (const float*)d_in[25];
  const float* end2_b  = (const float*)d_in[26];
  float* out = (float*)d_out;

  float* ws = (float*)d_ws;
  // ---- Region R0: 33,554,432 floats. Prologue: fp32 att (becomes bf16 in place).
  //      Loop phase: act | bufP | bufQ | skip | Y.
  float* dyn = ws;
  unsigned short* act = (unsigned short*)ws;                 // 3,145,728 floats
  float* bufP = ws + 3145728;                                // 6,815,744
  float* bufQ = ws + 3145728 + 6815744;                      // 6,815,744
  float* skip = ws + 16777216;                               // 4,194,304
  unsigned short* Y = (unsigned short*)(ws + 20971520);      // 12,582,912 floats
  // ---- dynT region: 16,777,216 floats (33,554,432 bf16). Prologue alias: l/r.
  unsigned short* dynT = (unsigned short*)(ws + 33554432);
  float* lbuf = ws + 33554432;                               // 2,097,152 (alias)
  float* rbuf = ws + 33554432 + 2097152;                     // 2,097,152 (alias)
  // ---- supT: 524,288 floats.
  unsigned short* supT = (unsigned short*)(ws + 33554432 + 16777216);
  // ---- end-MLP buffers (used only after the layer loop):
  unsigned short* skT  = (unsigned short*)(ws + 50855936);   // 2,097,152 floats
  unsigned short* hid  = (unsigned short*)(ws + 52953088);   // 4,194,304 floats
  unsigned short* e1wB = (unsigned short*)(ws + 57147392);   //    65,536 floats
  unsigned short* e2wB = (unsigned short*)(ws + 57212928);   //     4,096 floats
  // total: 57,217,024 floats = 228.9 MB (< 237 MB proven-safe)

  hipLaunchKernelGGL(k_feat_lr, dim3(BB*NNODE), dim3(128), 0, stream,
                     input, emb, embds_w, embds_b, wl_w, wl_b, wr_w, wr_b, lbuf, rbuf);
  hipLaunchKernelGGL(k_att, dim3(16, 16, BB*NH), dim3(256), 0, stream, lbuf, rbuf, dyn);
  hipLaunchKernelGGL(k_topk_softmax, dim3(BB*NH*NNODE), dim3(256), 0, stream, dyn);
  hipLaunchKernelGGL(k_transpose_dyn, dim3(8, 8, BB*NH), dim3(256), 0, stream,
                     (const unsigned short*)dyn, dynT);
  hipLaunchKernelGGL(k_supT_copy, dim3(8, 8, 2), dim3(256), 0, stream, supports, supT);
  hipLaunchKernelGGL(k_supT_sq, dim3(16, 16, 2), dim3(256), 0, stream, supports, supT);
  {
    int total = BB*RFP*CCH*NNODE;
    hipLaunchKernelGGL(k_make_x0, dim3((total+255)/256), dim3(256), 0, stream,
                       input, start_w, start_b, bufP);
  }
  {
    int n = BB*SKC*NNODE;
    hipLaunchKernelGGL(k_zero, dim3((n+255)/256), dim3(256), 0, stream, skip, n);
  }

  const int dil_[8] = {1,2,1,2,1,2,1,2};
  int T = RFP;
  float* P = bufP; float* Q = bufQ;
  for (int i = 0; i < NL; ++i){
    int d = dil_[i], Tp = T - d;
    int Mb = Tp*32;
    hipLaunchKernelGGL(k_dconv_act, dim3(8, Tp, BB), dim3(256), 0, stream,
        P, filter_w + i*2048, filter_b + i*32, gate_w + i*2048, gate_b + i*32,
        act, T, Tp, d);
    hipLaunchKernelGGL(k_skip_accum, dim3(8, 8, BB), dim3(256), 0, stream,
        act, skip_w + i*SKC*CCH, skip_b + i*SKC, skip, Tp);
    // dyn GCN: Y = act * dynT(b), then mix -> act (in place)
    hipLaunchKernelGGL(k_gemm, dim3(16, (Mb+127)/128, BB), dim3(256), 0, stream,
        act, dynT, Y, Mb, (long long)NH*NNODE*NNODE, 512, 2048, 0);
    hipLaunchKernelGGL(k_mix, dim3(BB*Tp), dim3(256), 0, stream,
        act, Y, dyn_w + i*5120, dyn_b + i*32,
        act, (float*)nullptr, (const float*)nullptr, (const float*)nullptr,
        (const float*)nullptr, Tp, d);
    // sup GCN: Y = act * supT, then mix (+residual+bn) -> Q fp32
    hipLaunchKernelGGL(k_gemm, dim3(16, (Mb+127)/128, BB), dim3(256), 0, stream,
        act, supT, Y, Mb, 0LL, 512, 2048, 0);
    hipLaunchKernelGGL(k_mix, dim3(BB*Tp), dim3(256), 0, stream,
        act, Y, gconv_w + i*5120, gconv_b + i*32,
        (unsigned short*)nullptr, Q, P, bn_g + i*32, bn_b + i*32, Tp, d);
    float* tmp = P; P = Q; Q = tmp;
    T = Tp;
  }
  // ---- end MLP: skipT -> MFMA end1 (relu) -> MFMA end2 ----
  hipLaunchKernelGGL(k_skipT, dim3(8, 4, BB), dim3(256), 0, stream, skip, skT);
  hipLaunchKernelGGL(k_cvt, dim3((ENDC*SKC+255)/256), dim3(256), 0, stream,
                     end1_w, e1wB, ENDC*SKC);
  hipLaunchKernelGGL(k_cvt_e2, dim3((16*ENDC+255)/256), dim3(256), 0, stream,
                     end2_w, e2wB);
  hipLaunchKernelGGL(k_gemm, dim3(4, 128, 1), dim3(256), 0, stream,
      skT, e1wB, hid, BB*NNODE, 0LL, 256, 512, 1);
  hipLaunchKernelGGL(k_end2, dim3(256), dim3(256), 0, stream, hid, e2wB, end1_b, out);
}

// Round 7
// 1799.400 us; speedup vs baseline: 4.4416x; 1.3062x over previous
//
#include <hip/hip_runtime.h>
#include <math.h>

#define BB 32
#define NNODE 512
#define TIN 12
#define CCH 32
#define NH 4
#define DDIM 32
#define NL 8
#define SKC 256
#define ENDC 512
#define ODIM 12
#define RFP 13

typedef __attribute__((ext_vector_type(8))) short bf16x8;
typedef __attribute__((ext_vector_type(4))) float f32x4;

__device__ __forceinline__ float sigmoidf_(float x){ return 1.0f/(1.0f+expf(-x)); }
__device__ __forceinline__ unsigned short f2bf(float f){
  unsigned u = __float_as_uint(f);
  u += 0x7FFFu + ((u >> 16) & 1u);
  return (unsigned short)(u >> 16);
}
__device__ __forceinline__ float bf2f(unsigned short h){
  return __uint_as_float(((unsigned)h) << 16);
}
__device__ __forceinline__ void gload16(const void* g, void* l){
  __builtin_amdgcn_global_load_lds(
      (const __attribute__((address_space(1))) void*)g,
      (__attribute__((address_space(3))) void*)l, 16, 0, 0);
}

// ---------------- feature -> l, r ----------------
__global__ void k_feat_lr(const float* __restrict__ input, const float* __restrict__ emb,
                          const float* __restrict__ embds_w, const float* __restrict__ embds_b,
                          const float* __restrict__ wl_w, const float* __restrict__ wl_b,
                          const float* __restrict__ wr_w, const float* __restrict__ wr_b,
                          float* __restrict__ lbuf, float* __restrict__ rbuf){
  int bn = blockIdx.x;          // b*N + n
  int b = bn >> 9, n = bn & 511;
  int j = threadIdx.x;          // 0..127
  __shared__ float f[TIN];
  if (j < TIN){
    float s = 0.f;
    for (int t = 0; t < TIN; ++t) s += input[(b*TIN + t)*NNODE + n] * embds_w[t];
    f[j] = s + embds_b[0] + emb[n*TIN + j];
  }
  __syncthreads();
  float lv = wl_b[j], rv = wr_b[j];
  for (int t = 0; t < TIN; ++t){
    float ft = f[t];
    lv += ft * wl_w[t*128 + j];
    rv += ft * wr_w[t*128 + j];
  }
  int h = j >> 5, d = j & 31;
  int o = ((b*NH + h)*NNODE + n)*DDIM + d;
  lbuf[o] = lv; rbuf[o] = rv;
}

// ---------------- att = l r^T / sqrt(32), 32x32 tiles ----------------
__global__ __launch_bounds__(256) void k_att(const float* __restrict__ lbuf,
                      const float* __restrict__ rbuf, float* __restrict__ att){
  int bh = blockIdx.z;
  int n0 = blockIdx.y * 32, m0 = blockIdx.x * 32;
  int tid = threadIdx.x;
  int tx = tid & 31, ty = tid >> 5;   // 8 row-groups
  __shared__ float Ls[32][33], Rs[32][33];
  const float* lb = lbuf + (size_t)bh*NNODE*DDIM;
  const float* rb = rbuf + (size_t)bh*NNODE*DDIM;
  for (int i = tid; i < 1024; i += 256){
    int r = i >> 5, c = i & 31;
    Ls[r][c] = lb[(n0+r)*DDIM + c];
    Rs[r][c] = rb[(m0+r)*DDIM + c];
  }
  __syncthreads();
  float acc[4] = {0.f,0.f,0.f,0.f};
  for (int d = 0; d < 32; ++d){
    float rv = Rs[tx][d];
    #pragma unroll
    for (int j = 0; j < 4; ++j) acc[j] += Ls[ty + 8*j][d] * rv;
  }
  #pragma unroll
  for (int j = 0; j < 4; ++j)
    att[((size_t)bh*NNODE + n0+ty+8*j)*NNODE + m0 + tx] = acc[j] / sqrtf(32.0f);
}

// -------- per-WAVE exact top-k radix select + softmax; bf16 out in place --------
__global__ __launch_bounds__(256) void k_topk_softmax(float* __restrict__ att){
  __shared__ int hist[4*256];
  int tid = threadIdx.x;
  int wid = tid >> 6, lane = tid & 63;
  int row = blockIdx.x*4 + wid;         // (b*H + h)*N + n
  int h = (row >> 9) & 3;
  int k = (h==0)?10:(h==1)?20:(h==2)?40:500;
  float* rp = att + (size_t)row * NNODE;
  int* hh = hist + wid*256;
  float v[8]; unsigned a[8];
  #pragma unroll
  for (int j = 0; j < 8; ++j){
    v[j] = rp[j*64 + lane];
    unsigned u = __float_as_uint(v[j]);
    a[j] = (u & 0x80000000u) ? ~u : (u | 0x80000000u);
  }
  float m = v[0];
  #pragma unroll
  for (int j = 1; j < 8; ++j) m = fmaxf(m, v[j]);
  for (int off = 32; off; off >>= 1) m = fmaxf(m, __shfl_down(m, off, 64));
  float mx = __shfl(m, 0, 64);
  unsigned pfx = 0u; int kr = k;
  for (int rnd = 0; rnd < 4; ++rnd){
    int sh = 24 - rnd*8;
    #pragma unroll
    for (int i = 0; i < 4; ++i) hh[lane*4+i] = 0;
    __builtin_amdgcn_wave_barrier();
    #pragma unroll
    for (int j = 0; j < 8; ++j){
      bool c = (rnd == 0) || ((a[j] >> (sh+8)) == (pfx >> (sh+8)));
      if (c) atomicAdd(&hh[(a[j] >> sh) & 255], 1);
    }
    __builtin_amdgcn_wave_barrier();
    asm volatile("s_waitcnt lgkmcnt(0)" ::: "memory");
    int h0 = hh[lane*4], h1 = hh[lane*4+1], h2 = hh[lane*4+2], h3 = hh[lane*4+3];
    int s3 = h3, s2 = h2+s3, s1 = h1+s2, s0 = h0+s1;
    int t = s0;
    #pragma unroll
    for (int off = 1; off < 64; off <<= 1){
      int y = __shfl_down(t, off, 64);
      if (lane + off < 64) t += y;
    }
    int Asuf = __shfl_down(t, 1, 64);
    if (lane == 63) Asuf = 0;
    int cs0 = s0+Asuf, cs1 = s1+Asuf, cs2 = s2+Asuf, cs3 = s3+Asuf;
    int found = 0, dloc = 0, krloc = 0;
    if (cs0 >= kr && cs0-h0 < kr){ found=1; dloc=lane*4+0; krloc = kr-(cs0-h0); }
    if (cs1 >= kr && cs1-h1 < kr){ found=1; dloc=lane*4+1; krloc = kr-(cs1-h1); }
    if (cs2 >= kr && cs2-h2 < kr){ found=1; dloc=lane*4+2; krloc = kr-(cs2-h2); }
    if (cs3 >= kr && cs3-h3 < kr){ found=1; dloc=lane*4+3; krloc = kr-(cs3-h3); }
    unsigned long long msk = __ballot(found);
    int src = __ffsll((unsigned long long)msk) - 1;
    int db = __shfl(dloc, src, 64);
    kr = __shfl(krloc, src, 64);
    pfx = pfx | ((unsigned)db << sh);
  }
  unsigned uth = pfx; int neq = kr;   // ties kept, lowest index first
  unsigned long long em[8];
  #pragma unroll
  for (int j = 0; j < 8; ++j) em[j] = __ballot(a[j] == uth);
  int pcum[8]; int run = 0;
  #pragma unroll
  for (int j = 0; j < 8; ++j){ pcum[j] = run; run += (int)__popcll(em[j]); }
  unsigned long long below = (1ull << lane) - 1ull;
  float e[8]; float ssum = 0.f;
  #pragma unroll
  for (int j = 0; j < 8; ++j){
    bool kp = a[j] > uth;
    if (!kp && a[j] == uth){
      int rank = pcum[j] + (int)__popcll(em[j] & below);
      kp = rank < neq;
    }
    e[j] = kp ? expf(v[j] - mx) : 0.f;
    ssum += e[j];
  }
  for (int off = 32; off; off >>= 1) ssum += __shfl_down(ssum, off, 64);
  float tot = __shfl(ssum, 0, 64);
  unsigned short* rp16 = (unsigned short*)rp;
  #pragma unroll
  for (int j = 0; j < 8; ++j) rp16[j*64 + lane] = f2bf(e[j] / tot);
}

// ------- transpose dynBf (bf16 rows, stride 1024 shorts) -> dynT (bf16 [bs][w][v]) -------
__global__ __launch_bounds__(256) void k_transpose_dyn(const unsigned short* __restrict__ dynBf,
                                                       unsigned short* __restrict__ dynT){
  int bs = blockIdx.z;
  int v0 = blockIdx.x*64, w0 = blockIdx.y*64;
  __shared__ unsigned short Ts[64][66];
  const unsigned short* S = dynBf + (size_t)bs*NNODE*1024;
  unsigned short* D = dynT + (size_t)bs*NNODE*NNODE;
  int tid = threadIdx.x;
  for (int i = tid; i < 4096; i += 256){
    int r = i >> 6, c = i & 63;
    Ts[r][c] = S[(size_t)(v0+r)*1024 + w0 + c];
  }
  __syncthreads();
  for (int i = tid; i < 4096; i += 256){
    int r = i >> 6, c = i & 63;
    D[(size_t)(w0+r)*NNODE + v0 + c] = Ts[c][r];
  }
}

// ---------------- supT: transpose s0, s1 into blocks 0, 2 ----------------
__global__ __launch_bounds__(256) void k_supT_copy(const float* __restrict__ supports,
                                                   unsigned short* __restrict__ supT){
  int w = blockIdx.z;                  // 0 -> s0 (block 0), 1 -> s1 (block 2)
  int v0 = blockIdx.x*64, n0 = blockIdx.y*64;
  __shared__ float Ts[64][65];
  const float* S = supports + (size_t)w*NNODE*NNODE;
  int tid = threadIdx.x;
  for (int i = tid; i < 4096; i += 256){
    int r = i >> 6, c = i & 63;
    Ts[r][c] = S[(size_t)(v0+r)*NNODE + n0 + c];
  }
  __syncthreads();
  for (int i = tid; i < 4096; i += 256){
    int r = i >> 6, c = i & 63;
    supT[((size_t)(2*w)*NNODE + n0 + r)*NNODE + v0 + c] = f2bf(Ts[c][r]);
  }
}

// ---------------- supT squares: s@s, transposed store into blocks 1, 3 ----------------
__global__ __launch_bounds__(256) void k_supT_sq(const float* __restrict__ supports,
                                                 unsigned short* __restrict__ supT){
  int which = blockIdx.z;              // 0 -> s0^2 (block 1), 1 -> s1^2 (block 3)
  const float* A = supports + (size_t)which*NNODE*NNODE;
  int w0 = blockIdx.x * 32, v0 = blockIdx.y * 32;
  int tid = threadIdx.x;
  int tx = tid & 31, tyg = tid >> 5;
  __shared__ float As[32][33], Bs[32][33], Cs[32][33];
  float acc[4] = {0.f,0.f,0.f,0.f};
  for (int k0 = 0; k0 < NNODE; k0 += 32){
    int lc = tid >> 3, lu0 = (tid & 7) * 4;
    __syncthreads();
    for (int u = 0; u < 4; ++u){
      As[lc][lu0+u] = A[(size_t)(v0+lc)*NNODE + k0 + lu0 + u];
      Bs[lc][lu0+u] = A[(size_t)(k0+lc)*NNODE + w0 + lu0 + u];
    }
    __syncthreads();
    for (int u = 0; u < 32; ++u){
      float bw = Bs[u][tx];
      #pragma unroll
      for (int j = 0; j < 4; ++j) acc[j] += As[tyg + 8*j][u] * bw;
    }
  }
  __syncthreads();
  #pragma unroll
  for (int j = 0; j < 4; ++j) Cs[tyg + 8*j][tx] = acc[j];   // Cs[v_local][w_local]
  __syncthreads();
  for (int i = tid; i < 1024; i += 256){
    int wl = i >> 5, vl = i & 31;
    supT[((size_t)(2*which+1)*NNODE + w0 + wl)*NNODE + v0 + vl] = f2bf(Cs[vl][wl]);
  }
}

// ---------------- x0 = start conv on left-padded input ----------------
__global__ void k_make_x0(const float* __restrict__ input, const float* __restrict__ start_w,
                          const float* __restrict__ start_b, float* __restrict__ x0){
  int idx = blockIdx.x*256 + threadIdx.x;
  const int total = BB*RFP*CCH*NNODE;
  if (idx >= total) return;
  int n = idx & 511;
  int rest = idx >> 9;
  int c = rest & 31; rest >>= 5;
  int t = rest % RFP;
  int b = rest / RFP;
  float v = (t == 0) ? 0.f : input[((size_t)b*TIN + (t-1))*NNODE + n];
  x0[idx] = start_w[c] * v + start_b[c];
}

// ------- dilated conv + tanh*sigmoid gate -> bf16 act; skip fused at t==Tp-1 -------
__global__ __launch_bounds__(256) void k_dconv_act(const float* __restrict__ x,
      const float* __restrict__ fw, const float* __restrict__ fb,
      const float* __restrict__ gw, const float* __restrict__ gb,
      unsigned short* __restrict__ out,
      const float* __restrict__ sw, const float* __restrict__ sb,
      float* __restrict__ skip,
      int Tin, int Tp, int dil, int skipInit){
  int n0 = blockIdx.x * 64;
  int t = blockIdx.y;
  int b = blockIdx.z;
  int tid = threadIdx.x;
  int lane = tid & 63, cg = tid >> 6;
  __shared__ float X0[32][64], X1[32][64];
  __shared__ float fwl[32][32][2], gwl[32][32][2];
  __shared__ float gs[32][64];
  const float* xb0 = x + ((size_t)(b*Tin + t)*CCH)*NNODE;
  const float* xb1 = x + ((size_t)(b*Tin + t + dil)*CCH)*NNODE;
  for (int i = tid; i < 32*64; i += 256){
    int c = i >> 6, nn2 = i & 63;
    X0[c][nn2] = xb0[c*NNODE + n0 + nn2];
    X1[c][nn2] = xb1[c*NNODE + n0 + nn2];
  }
  for (int i = tid; i < 2048; i += 256){
    ((float*)fwl)[i] = fw[i];
    ((float*)gwl)[i] = gw[i];
  }
  __syncthreads();
  float F[8], G[8];
  #pragma unroll
  for (int j = 0; j < 8; ++j){ int c = cg*8 + j; F[j] = fb[c]; G[j] = gb[c]; }
  for (int cp = 0; cp < 32; ++cp){
    float x0v = X0[cp][lane], x1v = X1[cp][lane];
    #pragma unroll
    for (int j = 0; j < 8; ++j){
      int c = cg*8 + j;
      F[j] += x0v * fwl[c][cp][0] + x1v * fwl[c][cp][1];
      G[j] += x0v * gwl[c][cp][0] + x1v * gwl[c][cp][1];
    }
  }
  unsigned short* ob = out + ((size_t)(b*Tp + t)*CCH)*NNODE;
  #pragma unroll
  for (int j = 0; j < 8; ++j){
    int c = cg*8 + j;
    float gv = tanhf(F[j]) * sigmoidf_(G[j]);
    gs[c][lane] = gv;
    ob[c*NNODE + n0 + lane] = f2bf(gv);
  }
  if (t == Tp - 1){
    __syncthreads();
    float* skb = skip + ((size_t)b*SKC)*NNODE + n0 + lane;
    for (int er = 0; er < 64; ++er){
      int e = cg*64 + er;
      float acc2 = sb[e];
      #pragma unroll
      for (int c = 0; c < 32; ++c) acc2 += sw[e*32 + c] * gs[c][lane];
      float* dst = skb + (size_t)e*NNODE;
      *dst = skipInit ? acc2 : (*dst + acc2);
    }
  }
}

// ------- fused GCN GEMM: Y = A*BT (K=512, B rows = (s,n)); epilogue mixes channels -------
// out[o,n] = bias[o] + sum_c Wx[o,c]*A[c,n] + sum_{s,c} Ws[o,c]*Y[c,(s,n)]
// dyn mode (outBf): write bf16 R.  sup mode (outF): +residual, *bn -> fp32 next-x.
__global__ __launch_bounds__(256) void k_gcn_gemm(
    const unsigned short* __restrict__ A, const unsigned short* __restrict__ BT,
    const float* __restrict__ w, const float* __restrict__ bias,
    unsigned short* __restrict__ outBf, float* __restrict__ outF,
    const float* __restrict__ res, const float* __restrict__ bng,
    const float* __restrict__ bnb, int Tp, int dil, long long bStride){
  __shared__ short smem[16384 + 5376];   // As(8192) Bs(8192) | Wcat(5376); Tt reuses As
  short* AsL = smem;
  short* BsL = smem + 8192;
  short* Wc  = smem + 16384;
  short* Tt  = smem;                     // 32*168 = 5376 <= 8192
  int tid = threadIdx.x;
  int b = blockIdx.z;
  int n032 = blockIdx.x * 32;
  int t0 = blockIdx.y * 4;
  int Mb = Tp * 32;
  int rowBase = b*Mb + blockIdx.y*128;
  const unsigned short* Bb = BT + (size_t)b * bStride;
  int wid = tid >> 6, lane = tid & 63;
  int wm = wid >> 1, wn = wid & 1;
  int l15 = lane & 15, l4 = lane >> 4;
  // stage Wcat[o][k]: k<128 -> w[o][32+k] (support weights), k>=128 -> w[o][k-128] (Wx)
  for (int i = tid; i < 5120; i += 256){
    int o = i / 160, kk = i - o*160;
    Wc[o*168 + kk] = (short)f2bf(w[o*160 + ((kk < 128) ? (32 + kk) : (kk - 128))]);
  }
  f32x4 acc[4][4];
  #pragma unroll
  for (int mf = 0; mf < 4; ++mf)
    #pragma unroll
    for (int nf = 0; nf < 4; ++nf)
      acc[mf][nf] = (f32x4){0.f, 0.f, 0.f, 0.f};
  for (int k0 = 0; k0 < 512; k0 += 64){
    __syncthreads();
    #pragma unroll
    for (int it = 0; it < 4; ++it){
      int r = it*32 + (tid>>3), g = tid & 7;
      gload16(A + (size_t)(rowBase + r)*512 + k0 + ((g ^ (r&7))<<3), AsL + r*64 + (g<<3));
      int s = r >> 5, nl = r & 31;
      gload16(Bb + (size_t)((s<<9) + n032 + nl)*512 + k0 + ((g ^ (r&7))<<3), BsL + r*64 + (g<<3));
    }
    __syncthreads();
    #pragma unroll
    for (int ks = 0; ks < 2; ++ks){
      bf16x8 af[4], bfr[4];
      #pragma unroll
      for (int mf = 0; mf < 4; ++mf){
        int rr = wm*64 + mf*16 + l15;
        af[mf] = *(const bf16x8*)(AsL + rr*64 + (((ks*4 + l4) ^ (rr & 7)) << 3));
      }
      #pragma unroll
      for (int nf = 0; nf < 4; ++nf){
        int rr = wn*64 + nf*16 + l15;
        bfr[nf] = *(const bf16x8*)(BsL + rr*64 + (((ks*4 + l4) ^ (rr & 7)) << 3));
      }
      #pragma unroll
      for (int mf = 0; mf < 4; ++mf)
        #pragma unroll
        for (int nf = 0; nf < 4; ++nf)
          acc[mf][nf] = __builtin_amdgcn_mfma_f32_16x16x32_bf16(af[mf], bfr[nf], acc[mf][nf], 0, 0, 0);
    }
  }
  const float inv = 1.0f / sqrtf(1.0f + 1e-5f);
  for (int t = 0; t < 4; ++t){
    __syncthreads();   // As/Bs (or prev Tt) free
    if (wm == (t >> 1)){
      #pragma unroll
      for (int mf2 = 0; mf2 < 2; ++mf2){
        int mf = (t & 1)*2 + mf2;
        #pragma unroll
        for (int nf = 0; nf < 4; ++nf){
          int c128 = wn*64 + nf*16 + l15;
          int s = c128 >> 5, nl = c128 & 31;
          #pragma unroll
          for (int r = 0; r < 4; ++r){
            int cROW = mf2*16 + l4*4 + r;
            Tt[nl*168 + s*32 + cROW] = (short)f2bf(acc[mf][nf][r]);
          }
        }
      }
    }
    // X^T chunk: cols 128..159 = A[c][n] transposed (the Wx term's input)
    for (int i = tid; i < 1024; i += 256){
      int c = i >> 5, nl = i & 31;
      Tt[nl*168 + 128 + c] =
        (short)A[(size_t)(b*Mb + (t0+t)*32 + c)*512 + n032 + nl];
    }
    __syncthreads();
    f32x4 am = (f32x4){0.f,0.f,0.f,0.f};
    #pragma unroll
    for (int ks = 0; ks < 5; ++ks){
      bf16x8 af = *(const bf16x8*)(Wc + (wm*16 + l15)*168 + ks*32 + l4*8);
      bf16x8 bf = *(const bf16x8*)(Tt + (wn*16 + l15)*168 + ks*32 + l4*8);
      am = __builtin_amdgcn_mfma_f32_16x16x32_bf16(af, bf, am, 0, 0, 0);
    }
    if (t0 + t < Tp){
      int btG = b*Tp + t0 + t;
      #pragma unroll
      for (int r = 0; r < 4; ++r){
        int o = wm*16 + l4*4 + r;
        int nl = wn*16 + l15;
        size_t oidx = (size_t)(btG*32 + o)*512 + n032 + nl;
        float val = am[r] + bias[o];
        if (outBf){
          outBf[oidx] = f2bf(val);
        } else {
          float resv = res[(size_t)((b*(Tp+dil) + t0 + t + dil)*32 + o)*512 + n032 + nl];
          outF[oidx] = (val + resv) * (bng[o]*inv) + bnb[o];
        }
      }
    }
  }
}

// ------- plain bf16 MFMA GEMM (used for end1): Y[m,n] = A[m,v]*BT[n,v] -------
__global__ __launch_bounds__(256) void k_gemm(
    const unsigned short* __restrict__ A, const unsigned short* __restrict__ BT,
    unsigned short* __restrict__ Y, int Mb, long long bStride,
    int K, int Ystride, int relu){
  __shared__ short As[128][64];
  __shared__ short Bs[128][64];
  int tid = threadIdx.x;
  int n0 = blockIdx.x * 128;
  int rowBase = blockIdx.z * Mb + blockIdx.y * 128;
  int rowEnd  = blockIdx.z * Mb + Mb;
  const unsigned short* Bb = BT + (size_t)blockIdx.z * bStride;
  int wid = tid >> 6, lane = tid & 63;
  int wm = wid >> 1, wn = wid & 1;
  int l15 = lane & 15, l4 = lane >> 4;
  f32x4 acc[4][4];
  #pragma unroll
  for (int mf = 0; mf < 4; ++mf)
    #pragma unroll
    for (int nf = 0; nf < 4; ++nf)
      acc[mf][nf] = (f32x4){0.f, 0.f, 0.f, 0.f};
  for (int k0 = 0; k0 < K; k0 += 64){
    __syncthreads();
    #pragma unroll
    for (int it = 0; it < 4; ++it){
      int r = it*32 + (tid>>3), g = tid & 7;
      gload16(A + (size_t)(rowBase + r)*K + k0 + ((g ^ (r&7))<<3), &As[r][g<<3]);
      gload16(Bb + (size_t)(n0 + r)*K + k0 + ((g ^ (r&7))<<3), &Bs[r][g<<3]);
    }
    __syncthreads();
    #pragma unroll
    for (int ks = 0; ks < 2; ++ks){
      bf16x8 af[4], bfr[4];
      #pragma unroll
      for (int mf = 0; mf < 4; ++mf){
        int r = wm*64 + mf*16 + l15;
        af[mf] = *(const bf16x8*)&As[r][(((ks*4 + l4) ^ (r & 7)) << 3)];
      }
      #pragma unroll
      for (int nf = 0; nf < 4; ++nf){
        int r = wn*64 + nf*16 + l15;
        bfr[nf] = *(const bf16x8*)&Bs[r][(((ks*4 + l4) ^ (r & 7)) << 3)];
      }
      #pragma unroll
      for (int mf = 0; mf < 4; ++mf)
        #pragma unroll
        for (int nf = 0; nf < 4; ++nf)
          acc[mf][nf] = __builtin_amdgcn_mfma_f32_16x16x32_bf16(af[mf], bfr[nf], acc[mf][nf], 0, 0, 0);
    }
  }
  #pragma unroll
  for (int mf = 0; mf < 4; ++mf){
    #pragma unroll
    for (int nf = 0; nf < 4; ++nf){
      #pragma unroll
      for (int r = 0; r < 4; ++r){
        int row = rowBase + wm*64 + mf*16 + l4*4 + r;
        if (row < rowEnd){
          int col = n0 + wn*64 + nf*16 + l15;
          float v = acc[mf][nf][r];
          if (relu) v = v > 0.f ? v : 0.f;
          Y[(size_t)row*Ystride + col] = f2bf(v);
        }
      }
    }
  }
}

// ---------------- skip -> relu -> bf16 transposed [(b,n), e] ----------------
__global__ __launch_bounds__(256) void k_skipT(const float* __restrict__ skip,
                                               unsigned short* __restrict__ skT){
  int b = blockIdx.z, e0 = blockIdx.y*64, n0 = blockIdx.x*64;
  __shared__ float Ts[64][65];
  int tid = threadIdx.x;
  for (int i = tid; i < 4096; i += 256){
    int r = i >> 6, c = i & 63;
    Ts[r][c] = skip[((size_t)b*SKC + e0 + r)*NNODE + n0 + c];
  }
  __syncthreads();
  for (int i = tid; i < 4096; i += 256){
    int r = i >> 6, c = i & 63;     // r = n-local, c = e-local
    float v = Ts[c][r];
    skT[((size_t)b*NNODE + n0 + r)*SKC + e0 + c] = f2bf(v > 0.f ? v : 0.f);
  }
}

// ---------------- fp32 -> bf16 weight converts ----------------
__global__ void k_cvt(const float* __restrict__ src, unsigned short* __restrict__ dst, int n){
  int i = blockIdx.x*256 + threadIdx.x;
  if (i < n) dst[i] = f2bf(src[i]);
}
__global__ void k_cvt_e2(const float* __restrict__ e2w, unsigned short* __restrict__ dst){
  int i = blockIdx.x*256 + threadIdx.x;   // 16*512
  if (i < 16*ENDC){
    int o = i >> 9;
    dst[i] = (o < ODIM) ? f2bf(e2w[(size_t)o*ENDC + (i & 511)]) : (unsigned short)0;
  }
}

// ---------------- end2: out[b,o,n] = e2b[o] + hid[(b,n),:]·e2w[o,:] ----------------
__global__ __launch_bounds__(256) void k_end2(const unsigned short* __restrict__ hid,
    const unsigned short* __restrict__ e2wB, const float* __restrict__ e2b,
    float* __restrict__ out){
  int rowBase = blockIdx.x * 64;
  int tid = threadIdx.x;
  int lane = tid & 63, w = tid >> 6;
  int l15 = lane & 15, l4 = lane >> 4;
  __shared__ unsigned short e2s[16][520];
  __shared__ float Cs[16][68];
  for (int i = tid; i < 4096; i += 256){
    int r = i >> 8, c2 = (i & 255) * 2;
    *(unsigned*)&e2s[r][c2] = *(const unsigned*)&e2wB[(size_t)r*ENDC + c2];
  }
  __syncthreads();
  f32x4 acc = (f32x4){0.f,0.f,0.f,0.f};
  const unsigned short* Ab = hid + (size_t)(rowBase + w*16 + l15)*ENDC;
  #pragma unroll
  for (int kk = 0; kk < 16; ++kk){
    bf16x8 af = *(const bf16x8*)(Ab + kk*32 + l4*8);
    bf16x8 bf = *(const bf16x8*)&e2s[l15][kk*32 + l4*8];
    acc = __builtin_amdgcn_mfma_f32_16x16x32_bf16(af, bf, acc, 0, 0, 0);
  }
  #pragma unroll
  for (int r = 0; r < 4; ++r)
    Cs[l15][w*16 + l4*4 + r] = acc[r];
  __syncthreads();
  for (int i = tid; i < ODIM*64; i += 256){
    int o = i >> 6, nl = i & 63;
    int gr = rowBase + nl;
    int b = gr >> 9, n = gr & 511;
    out[((size_t)(b*ODIM + o))*NNODE + n] = Cs[o][nl] + e2b[o];
  }
}

extern "C" void kernel_launch(void* const* d_in, const int* in_sizes, int n_in,
                              void* d_out, int out_size, void* d_ws, size_t ws_size,
                              hipStream_t stream){
  const float* input   = (const float*)d_in[0];
  const float* supports= (const float*)d_in[1];
  const float* emb     = (const float*)d_in[2];
  const float* embds_w = (const float*)d_in[3];
  const float* embds_b = (const float*)d_in[4];
  const float* wl_w    = (const float*)d_in[5];
  const float* wl_b    = (const float*)d_in[6];
  const float* wr_w    = (const float*)d_in[7];
  const float* wr_b    = (const float*)d_in[8];
  const float* start_w = (const float*)d_in[9];
  const float* start_b = (const float*)d_in[10];
  const float* filter_w= (const float*)d_in[11];
  const float* filter_b= (const float*)d_in[12];
  const float* gate_w  = (const float*)d_in[13];
  const float* gate_b  = (const float*)d_in[14];
  const float* skip_w  = (const float*)d_in[15];
  const float* skip_b  = (const float*)d_in[16];
  const float* bn_g    = (const float*)d_in[17];
  const float* bn_b    = (const float*)d_in[18];
  const float* gconv_w = (const float*)d_in[19];
  const float* gconv_b = (const float*)d_in[20];
  const float* dyn_w   = (const float*)d_in[21];
  const float* dyn_b   = (const float*)d_in[22];
  const float* end1_w  = (const float*)d_in[23];
  const float* end1_b  = (const float*)d_in[24];
  const float* end2_w  = (const float*)d_in[25];
  const float* end2_b  = (const float*)d_in[26];
  float* out = (float*)d_out;

  float* ws = (float*)d_ws;
  // ---- Region R0: 33,554,432 floats. Prologue: fp32 att (becomes bf16 in place).
  //      Loop phase: act | bufP | bufQ | skip | R.
  float* dyn = ws;
  unsigned short* act = (unsigned short*)ws;                 // 3,145,728 floats
  float* bufP = ws + 3145728;                                // 6,815,744
  float* bufQ = ws + 3145728 + 6815744;                      // 6,815,744
  float* skip = ws + 16777216;                               // 4,194,304
  unsigned short* R = (unsigned short*)(ws + 20971520);      // 3,145,728 floats (in old Y region)
  // ---- dynT region: 16,777,216 floats (33,554,432 bf16). Prologue alias: l/r.
  unsigned short* dynT = (unsigned short*)(ws + 33554432);
  float* lbuf = ws + 33554432;                               // 2,097,152 (alias)
  float* rbuf = ws + 33554432 + 2097152;                     // 2,097,152 (alias)
  // ---- supT: 524,288 floats.
  unsigned short* supT = (unsigned short*)(ws + 33554432 + 16777216);
  // ---- end-MLP buffers (used only after the layer loop):
  unsigned short* skT  = (unsigned short*)(ws + 50855936);   // 2,097,152 floats
  unsigned short* hid  = (unsigned short*)(ws + 52953088);   // 4,194,304 floats
  unsigned short* e1wB = (unsigned short*)(ws + 57147392);   //    65,536 floats
  unsigned short* e2wB = (unsigned short*)(ws + 57212928);   //     4,096 floats
  // total: 57,217,024 floats = 228.9 MB (proven-safe)

  hipLaunchKernelGGL(k_feat_lr, dim3(BB*NNODE), dim3(128), 0, stream,
                     input, emb, embds_w, embds_b, wl_w, wl_b, wr_w, wr_b, lbuf, rbuf);
  hipLaunchKernelGGL(k_att, dim3(16, 16, BB*NH), dim3(256), 0, stream, lbuf, rbuf, dyn);
  hipLaunchKernelGGL(k_topk_softmax, dim3(BB*NH*NNODE/4), dim3(256), 0, stream, dyn);
  hipLaunchKernelGGL(k_transpose_dyn, dim3(8, 8, BB*NH), dim3(256), 0, stream,
                     (const unsigned short*)dyn, dynT);
  hipLaunchKernelGGL(k_supT_copy, dim3(8, 8, 2), dim3(256), 0, stream, supports, supT);
  hipLaunchKernelGGL(k_supT_sq, dim3(16, 16, 2), dim3(256), 0, stream, supports, supT);
  {
    int total = BB*RFP*CCH*NNODE;
    hipLaunchKernelGGL(k_make_x0, dim3((total+255)/256), dim3(256), 0, stream,
                       input, start_w, start_b, bufP);
  }

  const int dil_[8] = {1,2,1,2,1,2,1,2};
  int T = RFP;
  float* P = bufP; float* Q = bufQ;
  for (int i = 0; i < NL; ++i){
    int d = dil_[i], Tp = T - d;
    int mT = (Tp*32 + 127)/128;
    hipLaunchKernelGGL(k_dconv_act, dim3(8, Tp, BB), dim3(256), 0, stream,
        P, filter_w + i*2048, filter_b + i*32, gate_w + i*2048, gate_b + i*32,
        act, skip_w + i*SKC*CCH, skip_b + i*SKC, skip, T, Tp, d, (i==0)?1:0);
    // dyn GCN + mix -> R (bf16)
    hipLaunchKernelGGL(k_gcn_gemm, dim3(16, mT, BB), dim3(256), 0, stream,
        act, dynT, dyn_w + i*5120, dyn_b + i*32,
        R, (float*)nullptr, (const float*)nullptr, (const float*)nullptr,
        (const float*)nullptr, Tp, d, (long long)NH*NNODE*NNODE);
    // sup GCN + mix + residual + bn -> Q (fp32)
    hipLaunchKernelGGL(k_gcn_gemm, dim3(16, mT, BB), dim3(256), 0, stream,
        R, supT, gconv_w + i*5120, gconv_b + i*32,
        (unsigned short*)nullptr, Q, P, bn_g + i*32, bn_b + i*32, Tp, d, 0LL);
    float* tmp = P; P = Q; Q = tmp;
    T = Tp;
  }
  // ---- end MLP: skipT -> MFMA end1 (relu) -> MFMA end2 ----
  hipLaunchKernelGGL(k_skipT, dim3(8, 4, BB), dim3(256), 0, stream, skip, skT);
  hipLaunchKernelGGL(k_cvt, dim3((ENDC*SKC+255)/256), dim3(256), 0, stream,
                     end1_w, e1wB, ENDC*SKC);
  hipLaunchKernelGGL(k_cvt_e2, dim3((16*ENDC+255)/256), dim3(256), 0, stream,
                     end2_w, e2wB);
  hipLaunchKernelGGL(k_gemm, dim3(4, 128, 1), dim3(256), 0, stream,
      skT, e1wB, hid, BB*NNODE, 0LL, 256, 512, 1);
  hipLaunchKernelGGL(k_end2, dim3(256), dim3(256), 0, stream, hid, e2wB, end1_b, out);
}